// Round 7
// baseline (3752.386 us; speedup 1.0000x reference)
//
#include <hip/hip_runtime.h>

#define N_NODES 100000
#define E_EDGES 1600000
#define F_IN    64
#define H_DIM   128
#define R_REL   20
#define G_GRAPHS 64
#define C_CLASSES 10
#define L_LAYERS 2
#define BN_EPS  1e-5f
#define RN      (R_REL * N_NODES)   // 2,000,000 (rel,dst) bins

typedef unsigned short u16;
typedef unsigned int   u32;
typedef __attribute__((ext_vector_type(8))) short short8;
typedef __attribute__((ext_vector_type(4))) float f32x4;

static __device__ __forceinline__ float bf2f(u16 u) {
    u32 b = ((u32)u) << 16;
    return __builtin_bit_cast(float, b);
}
static __device__ __forceinline__ u16 f2bf(float f) {
    u32 x = __builtin_bit_cast(u32, f);
    u32 r = x + 0x7fff + ((x >> 16) & 1);   // RNE; inputs finite
    return (u16)(r >> 16);
}

// ============================================================
// Edge preprocessing: histogram over (rel,dst), 3-level scan, counting sort
// ============================================================

__global__ void count_kernel(const int* __restrict__ ei, const int* __restrict__ et,
                             int* __restrict__ hist) {
    for (int e = blockIdx.x * blockDim.x + threadIdx.x; e < E_EDGES;
         e += gridDim.x * blockDim.x) {
        int t = et[e];
        int d = ei[E_EDGES + e];
        atomicAdd(&hist[t * N_NODES + d], 1);
    }
}

// exclusive scan, 1024 items / block
__global__ void scan1_kernel(const int* __restrict__ in, int* __restrict__ out,
                             int* __restrict__ part, int n) {
    __shared__ int s[256];
    int t = threadIdx.x;
    int base = blockIdx.x * 1024;
    int v[4]; int sum = 0;
#pragma unroll
    for (int j = 0; j < 4; ++j) {
        int i = base + t * 4 + j;
        v[j] = (i < n) ? in[i] : 0;
        sum += v[j];
    }
    s[t] = sum;
    __syncthreads();
    for (int off = 1; off < 256; off <<= 1) {
        int x = (t >= off) ? s[t - off] : 0;
        __syncthreads();
        s[t] += x;
        __syncthreads();
    }
    if (t == 255) part[blockIdx.x] = s[255];
    int run = s[t] - sum;
#pragma unroll
    for (int j = 0; j < 4; ++j) {
        int i = base + t * 4 + j;
        if (i < n) out[i] = run;
        run += v[j];
    }
}

// exclusive scan of up to 2048 partials in one block (8/thread)
__global__ void scan2_kernel(int* __restrict__ part, int nb) {
    __shared__ int s[256];
    int t = threadIdx.x;
    int loc[8]; int sum = 0;
#pragma unroll
    for (int j = 0; j < 8; ++j) {
        int i = t * 8 + j;
        loc[j] = (i < nb) ? part[i] : 0;
        sum += loc[j];
    }
    s[t] = sum;
    __syncthreads();
    for (int off = 1; off < 256; off <<= 1) {
        int x = (t >= off) ? s[t - off] : 0;
        __syncthreads();
        s[t] += x;
        __syncthreads();
    }
    int run = s[t] - sum;
#pragma unroll
    for (int j = 0; j < 8; ++j) {
        int i = t * 8 + j;
        if (i < nb) part[i] = run;
        run += loc[j];
    }
}

// add block bases; mirror into cur2 (atomic cursors for the sort)
__global__ void scan3_kernel(int* __restrict__ out, int* __restrict__ cur2,
                             const int* __restrict__ part, int n) {
    for (int i = blockIdx.x * blockDim.x + threadIdx.x; i < n;
         i += gridDim.x * blockDim.x) {
        int v = out[i] + part[i >> 10];
        out[i] = v;
        cur2[i] = v;
    }
}

__global__ void finalize_kernel(int* __restrict__ off2) {
    if (threadIdx.x == 0) off2[RN] = E_EDGES;
}

// counting sort into (rel,dst) order; per-edge {src, dst} pair
__global__ void bucket_kernel(const int* __restrict__ ei, const int* __restrict__ et,
                              int* __restrict__ cur2, int2* __restrict__ epair) {
    for (int e = blockIdx.x * blockDim.x + threadIdx.x; e < E_EDGES;
         e += gridDim.x * blockDim.x) {
        int t = et[e];
        int s = ei[e];
        int d = ei[E_EDGES + e];
        int pos = atomicAdd(&cur2[t * N_NODES + d], 1);
        epair[pos] = make_int2(s, d);
    }
}

// ============================================================
// Weight pack: fp32 [K,128] -> bf16 MFMA-frag order (verified R2-R5)
// ============================================================
template<int K>
__global__ void pack_w(const float* __restrict__ W, u16* __restrict__ Wp) {
    const float* w = W + (size_t)blockIdx.x * K * H_DIM;
    u16* p = Wp + (size_t)blockIdx.x * K * H_DIM;
    for (int o = threadIdx.x; o < K * H_DIM; o += blockDim.x) {
        int j  = o & 7;
        int l  = (o >> 3) & 63;
        int ct = (o >> 9) & 7;
        int kt = o >> 12;
        int k  = kt * 32 + (l >> 4) * 8 + j;
        int n  = ct * 16 + (l & 15);
        p[o] = f2bf(w[(size_t)k * H_DIM + n]);
    }
}

__global__ void cvt_bf16_kernel(const float* __restrict__ in, u16* __restrict__ out, int n4) {
    for (int i = blockIdx.x * blockDim.x + threadIdx.x; i < n4;
         i += gridDim.x * blockDim.x) {
        float4 v = ((const float4*)in)[i];
        ushort4 o;
        o.x = f2bf(v.x); o.y = f2bf(v.y); o.z = f2bf(v.z); o.w = f2bf(v.w);
        ((ushort4*)out)[i] = o;
    }
}

// ============================================================
// Dense MFMA GEMM (input MLP) — proven R2-R5 structure
// ============================================================
template<int K, bool RELU, bool HASBIAS, bool OUTBF16>
__global__ __launch_bounds__(256)
void mfma_dense(const u16* __restrict__ A, const u16* __restrict__ Wp,
                const float* __restrict__ bias, void* __restrict__ OutV, int M) {
    constexpr int CH = K / 8;
    __shared__ u16 Ws[K * H_DIM];
    __shared__ u16 As[64 * H_DIM];

    for (int o = threadIdx.x; o < K * H_DIM / 8; o += 256)
        ((short8*)Ws)[o] = ((const short8*)Wp)[o];

    const int lane = threadIdx.x & 63;
    const int wave = threadIdx.x >> 6;
    const int l15  = lane & 15;
    const int kgrp = lane >> 4;
    const int arow = wave * 16 + l15;

    for (int tb = blockIdx.x * 64; tb < M; tb += gridDim.x * 64) {
        __syncthreads();
        for (int o = threadIdx.x; o < 64 * CH; o += 256) {
            int row = o / CH, cc = o % CH;
            int grow = tb + row;
            short8 v = {0,0,0,0,0,0,0,0};
            if (grow < M) v = *(const short8*)&A[(size_t)grow * K + cc * 8];
            *(short8*)&As[row * K + ((cc ^ (row & 7)) * 8)] = v;
        }
        __syncthreads();

        f32x4 acc[8];
#pragma unroll
        for (int i = 0; i < 8; ++i) {
            acc[i][0] = 0.f; acc[i][1] = 0.f; acc[i][2] = 0.f; acc[i][3] = 0.f;
        }
#pragma unroll
        for (int kt = 0; kt < K / 32; ++kt) {
            short8 af = *(const short8*)&As[arow * K + (((kt * 4 + kgrp) ^ (arow & 7)) * 8)];
#pragma unroll
            for (int ct = 0; ct < 8; ++ct) {
                short8 bf = *(const short8*)&Ws[(((kt * 8 + ct) * 64) + lane) * 8];
                acc[ct] = __builtin_amdgcn_mfma_f32_16x16x32_bf16(af, bf, acc[ct], 0, 0, 0);
            }
        }

        if (OUTBF16) {
            __syncthreads();
#pragma unroll
            for (int ct = 0; ct < 8; ++ct) {
#pragma unroll
                for (int r = 0; r < 4; ++r) {
                    int row = wave * 16 + kgrp * 4 + r;
                    int col = ct * 16 + l15;
                    float v = acc[ct][r];
                    if (HASBIAS) v += bias[col];
                    if (RELU)    v = fmaxf(v, 0.f);
                    As[row * H_DIM + ((((col >> 3) ^ (row & 7)) << 3) | (col & 7))] = f2bf(v);
                }
            }
            __syncthreads();
            u16* Out = (u16*)OutV;
            for (int o = threadIdx.x; o < 64 * 16; o += 256) {
                int row = o >> 4, cc = o & 15;
                int grow = tb + row;
                if (grow < M)
                    *(short8*)&Out[(size_t)grow * H_DIM + cc * 8] =
                        *(const short8*)&As[row * H_DIM + ((cc ^ (row & 7)) << 3)];
            }
        } else {
            float* Out = (float*)OutV;
#pragma unroll
            for (int ct = 0; ct < 8; ++ct) {
#pragma unroll
                for (int r = 0; r < 4; ++r) {
                    int grow = tb + wave * 16 + kgrp * 4 + r;
                    if (grow < M) {
                        float v = acc[ct][r];
                        if (HASBIAS) v += bias[ct * 16 + l15];
                        if (RELU)    v = fmaxf(v, 0.f);
                        Out[(size_t)grow * H_DIM + ct * 16 + l15] = v;
                    }
                }
            }
        }
    }
}

// ============================================================
// Fused RGCN conv (v3): block owns 64 dst rows; per relation:
//   EDGE-PARALLEL accumulate: waves stride the (rel,dst)-sorted segment;
//   each edge = one coalesced 256B h-row load + 2x ds_add_f32 into a
//   64x128 fp32 LDS tile (XOR-chunk swizzled). Independent edges ->
//   loads pipeline; masks not branches. MFMA reads the f32 tile directly
//   (x 1/cnt, cvt to bf16 frags in regs), accumulating over 20 relations
//   + root (A from global h). 2 barriers/relation; each wave zeroes the
//   stripe it read. LDS 64KB -> 2 blocks/CU.
// ============================================================
#define EU 8
__global__ __launch_bounds__(256, 2)
void rgcn_conv(const u16* __restrict__ h, const u16* __restrict__ Wrel,
               const u16* __restrict__ Wroot, const float* __restrict__ bias,
               const int2* __restrict__ epair, const int* __restrict__ off2,
               float* __restrict__ outb) {
    __shared__ float T[64 * H_DIM];        // 32 KB fp32 accumulation tile
    __shared__ u16 Ws[H_DIM * H_DIM];      // 32 KB frag-packed W

    const int d0   = blockIdx.x * 64;
    const int dend = min(d0 + 64, N_NODES);
    const int lane = threadIdx.x & 63;
    const int wv   = threadIdx.x >> 6;     // 0..3
    const int l15  = lane & 15;
    const int kgrp = lane >> 4;
    const int arow = wv * 16 + l15;        // 0..63
    const u32* h2  = (const u32*)h;

    // initial zero of T
    f32x4 zz; zz[0] = 0.f; zz[1] = 0.f; zz[2] = 0.f; zz[3] = 0.f;
#pragma unroll
    for (int i = 0; i < 8; ++i)
        ((f32x4*)T)[i * 256 + threadIdx.x] = zz;

    f32x4 acc[8];
#pragma unroll
    for (int i = 0; i < 8; ++i) {
        acc[i][0] = 0.f; acc[i][1] = 0.f; acc[i][2] = 0.f; acc[i][3] = 0.f;
    }

    const int nmidx = min(d0 + arow, N_NODES - 1);   // per-lane count index

    for (int r = 0; r < R_REL; ++r) {
        const int base = r * N_NODES;
        const int s0 = off2[base + d0];
        const int s1 = off2[base + dend];
        __syncthreads();   // T zeroed / prev reads done, before new adds
        if (s1 > s0) {
            // per-lane bin-count loads (hidden under edge phase)
            const int c0 = off2[base + nmidx];
            const int c1 = off2[base + nmidx + 1];

            // edge-parallel accumulate (EU edges in flight per wave)
            for (int e = s0 + wv; e < s1; e += 4 * EU) {
                int   idx[EU];
                float msk[EU];
#pragma unroll
                for (int j = 0; j < EU; ++j) {
                    int ee = e + 4 * j;
                    idx[j] = min(ee, s1 - 1);
                    msk[j] = (ee < s1) ? 1.0f : 0.0f;
                }
                int2 p[EU];
#pragma unroll
                for (int j = 0; j < EU; ++j) p[j] = epair[idx[j]];
                u32 v[EU];
#pragma unroll
                for (int j = 0; j < EU; ++j)
                    v[j] = h2[(size_t)p[j].x * 64 + lane];
#pragma unroll
                for (int j = 0; j < EU; ++j) {
                    int row = p[j].y - d0;
                    int ci  = ((((lane >> 2) ^ (row & 7)) << 3) | (2 * (lane & 3)));
                    atomicAdd(&T[row * H_DIM + ci],     bf2f((u16)(v[j] & 0xffff)) * msk[j]);
                    atomicAdd(&T[row * H_DIM + ci + 1], bf2f((u16)(v[j] >> 16))    * msk[j]);
                }
            }

            // stage frag-packed W_r (after edge issue so it doesn't stall them)
            for (int o = threadIdx.x; o < H_DIM * H_DIM / 8; o += 256)
                ((short8*)Ws)[o] = ((const short8*)(Wrel + (size_t)r * H_DIM * H_DIM))[o];

            __syncthreads();   // adds + Ws visible

            const float nm = 1.0f / (float)max(c1 - c0, 1);
            // MFMA directly from the f32 tile: x nm, cvt to bf16 frags
#pragma unroll
            for (int kt = 0; kt < 4; ++kt) {
                int ch = (((kt * 4 + kgrp) ^ (arow & 7)) << 3);
                f32x4 lo = *(const f32x4*)&T[arow * H_DIM + ch];
                f32x4 hi = *(const f32x4*)&T[arow * H_DIM + ch + 4];
                short8 af;
                af[0] = (short)f2bf(lo[0] * nm); af[1] = (short)f2bf(lo[1] * nm);
                af[2] = (short)f2bf(lo[2] * nm); af[3] = (short)f2bf(lo[3] * nm);
                af[4] = (short)f2bf(hi[0] * nm); af[5] = (short)f2bf(hi[1] * nm);
                af[6] = (short)f2bf(hi[2] * nm); af[7] = (short)f2bf(hi[3] * nm);
#pragma unroll
                for (int ct = 0; ct < 8; ++ct) {
                    short8 bf = *(const short8*)&Ws[(((kt * 8 + ct) * 64) + lane) * 8];
                    acc[ct] = __builtin_amdgcn_mfma_f32_16x16x32_bf16(af, bf, acc[ct], 0, 0, 0);
                }
            }

            // zero own stripe (same wave that read it -> wave-local ordering)
#pragma unroll
            for (int i = 0; i < 8; ++i)
                *(f32x4*)&T[wv * (16 * H_DIM) + i * 256 + lane * 4] = zz;
        }
    }

    // ---- root "relation": A = h rows direct from global ----
    __syncthreads();
    for (int o = threadIdx.x; o < H_DIM * H_DIM / 8; o += 256)
        ((short8*)Ws)[o] = ((const short8*)Wroot)[o];
    __syncthreads();
    {
        const int hrow = min(d0 + arow, N_NODES - 1);
#pragma unroll
        for (int kt = 0; kt < 4; ++kt) {
            short8 af = *(const short8*)&h[(size_t)hrow * H_DIM + kt * 32 + kgrp * 8];
#pragma unroll
            for (int ct = 0; ct < 8; ++ct) {
                short8 bf = *(const short8*)&Ws[(((kt * 8 + ct) * 64) + lane) * 8];
                acc[ct] = __builtin_amdgcn_mfma_f32_16x16x32_bf16(af, bf, acc[ct], 0, 0, 0);
            }
        }
    }

    // ---- epilogue: outb = acc + bias (full overwrite) ----
#pragma unroll
    for (int ct = 0; ct < 8; ++ct) {
        float bv = bias[ct * 16 + l15];
#pragma unroll
        for (int rr = 0; rr < 4; ++rr) {
            int grow = d0 + wv * 16 + kgrp * 4 + rr;
            if (grow < N_NODES)
                outb[(size_t)grow * H_DIM + ct * 16 + l15] = acc[ct][rr] + bv;
        }
    }
}

// ============================================================
// BatchNorm + ReLU -> bf16 h
// ============================================================
__global__ void bn_reduce(const float* __restrict__ X, float* __restrict__ sums) {
    int col  = threadIdx.x & 127;
    int half = threadIdx.x >> 7;
    float s = 0.f, ss = 0.f;
    for (int row = blockIdx.x * 2 + half; row < N_NODES; row += gridDim.x * 2) {
        float v = X[(size_t)row * H_DIM + col];
        s += v; ss += v * v;
    }
    atomicAdd(&sums[col], s);
    atomicAdd(&sums[H_DIM + col], ss);
}

__global__ void bn_apply(const float* __restrict__ X, const float* __restrict__ sums,
                         const float* __restrict__ gg, const float* __restrict__ bb,
                         u16* __restrict__ Hout) {
    __shared__ float sc[H_DIM], sh[H_DIM];
    if (threadIdx.x < H_DIM) {
        float mean = sums[threadIdx.x] * (1.0f / N_NODES);
        float var  = sums[H_DIM + threadIdx.x] * (1.0f / N_NODES) - mean * mean;
        float inv  = rsqrtf(var + BN_EPS) * gg[threadIdx.x];
        sc[threadIdx.x] = inv;
        sh[threadIdx.x] = bb[threadIdx.x] - mean * inv;
    }
    __syncthreads();
    int total = N_NODES * (H_DIM / 4);
    for (int idx = blockIdx.x * 256 + threadIdx.x; idx < total; idx += gridDim.x * 256) {
        float4 v = ((const float4*)X)[idx];
        int c = (idx & 31) << 2;
        ushort4 o;
        o.x = f2bf(fmaxf(v.x * sc[c + 0] + sh[c + 0], 0.f));
        o.y = f2bf(fmaxf(v.y * sc[c + 1] + sh[c + 1], 0.f));
        o.z = f2bf(fmaxf(v.z * sc[c + 2] + sh[c + 2], 0.f));
        o.w = f2bf(fmaxf(v.w * sc[c + 3] + sh[c + 3], 0.f));
        ((ushort4*)Hout)[idx] = o;
    }
}

// ============================================================
// Pool + classifier
// ============================================================
__global__ void pool_kernel(const u16* __restrict__ Hf, const int* __restrict__ batch,
                            float* __restrict__ pool, float* __restrict__ pcnt) {
    int col  = threadIdx.x & 127;
    int half = threadIdx.x >> 7;
    int chunk = (N_NODES + gridDim.x - 1) / gridDim.x;
    int start = blockIdx.x * chunk;
    int end   = min(N_NODES, start + chunk);
    int curg = -1;
    float acc = 0.f, c = 0.f;
    for (int row = start + half; row < end; row += 2) {
        int g = batch[row];
        if (g != curg) {
            if (curg >= 0) {
                atomicAdd(&pool[curg * H_DIM + col], acc);
                if (col == 0) atomicAdd(&pcnt[curg], c);
            }
            curg = g; acc = 0.f; c = 0.f;
        }
        acc += bf2f(Hf[(size_t)row * H_DIM + col]);
        c += 1.f;
    }
    if (curg >= 0) {
        atomicAdd(&pool[curg * H_DIM + col], acc);
        if (col == 0) atomicAdd(&pcnt[curg], c);
    }
}

__global__ void logits_kernel(const float* __restrict__ pool, const float* __restrict__ pcnt,
                              const float* __restrict__ w_out, const float* __restrict__ b_out,
                              float* __restrict__ out) {
    int g = blockIdx.x;
    __shared__ float p[H_DIM];
    float cnt = fmaxf(pcnt[g], 1.0f);
    p[threadIdx.x] = pool[g * H_DIM + threadIdx.x] / cnt;
    __syncthreads();
    if (threadIdx.x < C_CLASSES) {
        float acc = b_out[threadIdx.x];
        for (int k = 0; k < H_DIM; ++k)
            acc += p[k] * w_out[k * C_CLASSES + threadIdx.x];
        out[g * C_CLASSES + threadIdx.x] = 1.0f / (1.0f + expf(-acc));
    }
}

// ============================================================
// Host launch
// ============================================================
static inline size_t align256(size_t x) { return (x + 255) & ~(size_t)255; }

extern "C" void kernel_launch(void* const* d_in, const int* in_sizes, int n_in,
                              void* d_out, int out_size, void* d_ws, size_t ws_size,
                              hipStream_t stream) {
    const float* x      = (const float*)d_in[0];
    const int*   ei     = (const int*)d_in[1];
    const int*   et     = (const int*)d_in[2];
    const int*   batch  = (const int*)d_in[3];
    const float* w_in   = (const float*)d_in[4];
    const float* b_in   = (const float*)d_in[5];
    const float* rel_w  = (const float*)d_in[6];
    const float* root_w = (const float*)d_in[7];
    const float* conv_b = (const float*)d_in[8];
    const float* bn_g   = (const float*)d_in[9];
    const float* bn_b   = (const float*)d_in[10];
    const float* w_out  = (const float*)d_in[11];
    const float* b_out  = (const float*)d_in[12];
    float* out = (float*)d_out;

    char* ws = (char*)d_ws;
    size_t off = 0;
    u16*   h_bf  = (u16*)(ws + off);  off += align256((size_t)N_NODES * H_DIM * 2);
    float* outb  = (float*)(ws + off); off += align256((size_t)N_NODES * H_DIM * 4);
    u16*   x_bf  = (u16*)(ws + off);  off += align256((size_t)N_NODES * F_IN * 2);
    int*   off2  = (int*)(ws + off);  off += align256((size_t)(RN + 1) * 4 + 256);
    int*   cur2  = (int*)(ws + off);  off += align256((size_t)RN * 4);
    int2*  e_pair = (int2*)(ws + off); off += align256((size_t)E_EDGES * 8 + 256);
    u16*   wp_in   = (u16*)(ws + off); off += align256((size_t)F_IN * H_DIM * 2);
    u16*   wp_root = (u16*)(ws + off); off += align256((size_t)L_LAYERS * H_DIM * H_DIM * 2);
    u16*   wp_rel  = (u16*)(ws + off); off += align256((size_t)L_LAYERS * R_REL * H_DIM * H_DIM * 2);
    int*   scan_part  = (int*)(ws + off); off += align256(2048 * 4);
    float* bn_sums    = (float*)(ws + off); off += align256(2 * H_DIM * 4);
    float* pool       = (float*)(ws + off); off += align256((size_t)G_GRAPHS * H_DIM * 4);
    float* pcnt       = (float*)(ws + off); off += 256;

    // ---- preprocessing: histogram -> scan -> (rel,dst) counting sort ----
    hipMemsetAsync(cur2, 0, (size_t)RN * 4, stream);    // cur2 doubles as histogram
    count_kernel<<<1024, 256, 0, stream>>>(ei, et, cur2);
    const int NB = (RN + 1023) / 1024;                   // 1954
    scan1_kernel<<<NB, 256, 0, stream>>>(cur2, off2, scan_part, RN);
    scan2_kernel<<<1, 256, 0, stream>>>(scan_part, NB);
    scan3_kernel<<<2048, 256, 0, stream>>>(off2, cur2, scan_part, RN);
    finalize_kernel<<<1, 64, 0, stream>>>(off2);
    bucket_kernel<<<2048, 256, 0, stream>>>(ei, et, cur2, e_pair);

    // ---- convert inputs / pack weights to bf16 ----
    cvt_bf16_kernel<<<2048, 256, 0, stream>>>(x, x_bf, N_NODES * F_IN / 4);
    pack_w<F_IN><<<1, 256, 0, stream>>>(w_in, wp_in);
    pack_w<H_DIM><<<L_LAYERS, 256, 0, stream>>>(root_w, wp_root);
    pack_w<H_DIM><<<L_LAYERS * R_REL, 256, 0, stream>>>(rel_w, wp_rel);

    // ---- input MLP: h = relu(x @ w_in + b_in) -> bf16 ----
    mfma_dense<F_IN, true, true, true><<<dim3(640), 256, 0, stream>>>(
        x_bf, wp_in, b_in, h_bf, N_NODES);

    // ---- RGCN layers (fused conv: edge-parallel LDS-atomic aggregation) ----
    const int CONV_BLOCKS = (N_NODES + 63) / 64;   // 1563
    for (int l = 0; l < L_LAYERS; ++l) {
        rgcn_conv<<<dim3(CONV_BLOCKS), 256, 0, stream>>>(
            h_bf, wp_rel + (size_t)l * R_REL * H_DIM * H_DIM,
            wp_root + (size_t)l * H_DIM * H_DIM, conv_b + (size_t)l * H_DIM,
            e_pair, off2, outb);
        hipMemsetAsync(bn_sums, 0, 2 * H_DIM * 4, stream);
        bn_reduce<<<512, 256, 0, stream>>>(outb, bn_sums);
        bn_apply<<<2048, 256, 0, stream>>>(outb, bn_sums,
                                           bn_g + (size_t)l * H_DIM,
                                           bn_b + (size_t)l * H_DIM, h_bf);
    }

    // ---- global mean pool + classifier ----
    hipMemsetAsync(pool, 0, (size_t)G_GRAPHS * H_DIM * 4, stream);
    hipMemsetAsync(pcnt, 0, 256, stream);
    pool_kernel<<<512, 256, 0, stream>>>(h_bf, batch, pool, pcnt);
    logits_kernel<<<G_GRAPHS, 128, 0, stream>>>(pool, pcnt, w_out, b_out, out);
}

// Round 8
// 940.813 us; speedup vs baseline: 3.9885x; 3.9885x over previous
//
#include <hip/hip_runtime.h>

#define N_NODES 100000
#define E_EDGES 1600000
#define F_IN    64
#define H_DIM   128
#define R_REL   20
#define G_GRAPHS 64
#define C_CLASSES 10
#define L_LAYERS 2
#define BN_EPS  1e-5f
#define RN      (R_REL * N_NODES)   // 2,000,000 (rel,dst) bins

typedef unsigned short u16;
typedef unsigned int   u32;
typedef __attribute__((ext_vector_type(8))) short short8;
typedef __attribute__((ext_vector_type(4))) float f32x4;

static __device__ __forceinline__ float bf2f(u16 u) {
    u32 b = ((u32)u) << 16;
    return __builtin_bit_cast(float, b);
}
static __device__ __forceinline__ u16 f2bf(float f) {
    u32 x = __builtin_bit_cast(u32, f);
    u32 r = x + 0x7fff + ((x >> 16) & 1);   // RNE; inputs finite
    return (u16)(r >> 16);
}

// ============================================================
// Edge preprocessing: histogram over (rel,dst), 3-level scan, counting sort
// ============================================================

__global__ void count_kernel(const int* __restrict__ ei, const int* __restrict__ et,
                             int* __restrict__ hist) {
    for (int e = blockIdx.x * blockDim.x + threadIdx.x; e < E_EDGES;
         e += gridDim.x * blockDim.x) {
        int t = et[e];
        int d = ei[E_EDGES + e];
        atomicAdd(&hist[t * N_NODES + d], 1);
    }
}

// exclusive scan, 1024 items / block
__global__ void scan1_kernel(const int* __restrict__ in, int* __restrict__ out,
                             int* __restrict__ part, int n) {
    __shared__ int s[256];
    int t = threadIdx.x;
    int base = blockIdx.x * 1024;
    int v[4]; int sum = 0;
#pragma unroll
    for (int j = 0; j < 4; ++j) {
        int i = base + t * 4 + j;
        v[j] = (i < n) ? in[i] : 0;
        sum += v[j];
    }
    s[t] = sum;
    __syncthreads();
    for (int off = 1; off < 256; off <<= 1) {
        int x = (t >= off) ? s[t - off] : 0;
        __syncthreads();
        s[t] += x;
        __syncthreads();
    }
    if (t == 255) part[blockIdx.x] = s[255];
    int run = s[t] - sum;
#pragma unroll
    for (int j = 0; j < 4; ++j) {
        int i = base + t * 4 + j;
        if (i < n) out[i] = run;
        run += v[j];
    }
}

// exclusive scan of up to 2048 partials in one block (8/thread)
__global__ void scan2_kernel(int* __restrict__ part, int nb) {
    __shared__ int s[256];
    int t = threadIdx.x;
    int loc[8]; int sum = 0;
#pragma unroll
    for (int j = 0; j < 8; ++j) {
        int i = t * 8 + j;
        loc[j] = (i < nb) ? part[i] : 0;
        sum += loc[j];
    }
    s[t] = sum;
    __syncthreads();
    for (int off = 1; off < 256; off <<= 1) {
        int x = (t >= off) ? s[t - off] : 0;
        __syncthreads();
        s[t] += x;
        __syncthreads();
    }
    int run = s[t] - sum;
#pragma unroll
    for (int j = 0; j < 8; ++j) {
        int i = t * 8 + j;
        if (i < nb) part[i] = run;
        run += loc[j];
    }
}

// add block bases; mirror into cur2 (atomic cursors for the sort)
__global__ void scan3_kernel(int* __restrict__ out, int* __restrict__ cur2,
                             const int* __restrict__ part, int n) {
    for (int i = blockIdx.x * blockDim.x + threadIdx.x; i < n;
         i += gridDim.x * blockDim.x) {
        int v = out[i] + part[i >> 10];
        out[i] = v;
        cur2[i] = v;
    }
}

__global__ void finalize_kernel(int* __restrict__ off2) {
    if (threadIdx.x == 0) off2[RN] = E_EDGES;
}

// counting sort into (rel,dst) order; per-edge {src, dst} pair
__global__ void bucket_kernel(const int* __restrict__ ei, const int* __restrict__ et,
                              int* __restrict__ cur2, int2* __restrict__ epair) {
    for (int e = blockIdx.x * blockDim.x + threadIdx.x; e < E_EDGES;
         e += gridDim.x * blockDim.x) {
        int t = et[e];
        int s = ei[e];
        int d = ei[E_EDGES + e];
        int pos = atomicAdd(&cur2[t * N_NODES + d], 1);
        epair[pos] = make_int2(s, d);
    }
}

// ============================================================
// Weight pack: fp32 [K,128] -> bf16 MFMA-frag order (verified R2-R5)
// ============================================================
template<int K>
__global__ void pack_w(const float* __restrict__ W, u16* __restrict__ Wp) {
    const float* w = W + (size_t)blockIdx.x * K * H_DIM;
    u16* p = Wp + (size_t)blockIdx.x * K * H_DIM;
    for (int o = threadIdx.x; o < K * H_DIM; o += blockDim.x) {
        int j  = o & 7;
        int l  = (o >> 3) & 63;
        int ct = (o >> 9) & 7;
        int kt = o >> 12;
        int k  = kt * 32 + (l >> 4) * 8 + j;
        int n  = ct * 16 + (l & 15);
        p[o] = f2bf(w[(size_t)k * H_DIM + n]);
    }
}

__global__ void cvt_bf16_kernel(const float* __restrict__ in, u16* __restrict__ out, int n4) {
    for (int i = blockIdx.x * blockDim.x + threadIdx.x; i < n4;
         i += gridDim.x * blockDim.x) {
        float4 v = ((const float4*)in)[i];
        ushort4 o;
        o.x = f2bf(v.x); o.y = f2bf(v.y); o.z = f2bf(v.z); o.w = f2bf(v.w);
        ((ushort4*)out)[i] = o;
    }
}

// ============================================================
// Dense MFMA GEMM (input MLP) — proven R2-R5 structure
// ============================================================
template<int K, bool RELU, bool HASBIAS, bool OUTBF16>
__global__ __launch_bounds__(256)
void mfma_dense(const u16* __restrict__ A, const u16* __restrict__ Wp,
                const float* __restrict__ bias, void* __restrict__ OutV, int M) {
    constexpr int CH = K / 8;
    __shared__ u16 Ws[K * H_DIM];
    __shared__ u16 As[64 * H_DIM];

    for (int o = threadIdx.x; o < K * H_DIM / 8; o += 256)
        ((short8*)Ws)[o] = ((const short8*)Wp)[o];

    const int lane = threadIdx.x & 63;
    const int wave = threadIdx.x >> 6;
    const int l15  = lane & 15;
    const int kgrp = lane >> 4;
    const int arow = wave * 16 + l15;

    for (int tb = blockIdx.x * 64; tb < M; tb += gridDim.x * 64) {
        __syncthreads();
        for (int o = threadIdx.x; o < 64 * CH; o += 256) {
            int row = o / CH, cc = o % CH;
            int grow = tb + row;
            short8 v = {0,0,0,0,0,0,0,0};
            if (grow < M) v = *(const short8*)&A[(size_t)grow * K + cc * 8];
            *(short8*)&As[row * K + ((cc ^ (row & 7)) * 8)] = v;
        }
        __syncthreads();

        f32x4 acc[8];
#pragma unroll
        for (int i = 0; i < 8; ++i) {
            acc[i][0] = 0.f; acc[i][1] = 0.f; acc[i][2] = 0.f; acc[i][3] = 0.f;
        }
#pragma unroll
        for (int kt = 0; kt < K / 32; ++kt) {
            short8 af = *(const short8*)&As[arow * K + (((kt * 4 + kgrp) ^ (arow & 7)) * 8)];
#pragma unroll
            for (int ct = 0; ct < 8; ++ct) {
                short8 bf = *(const short8*)&Ws[(((kt * 8 + ct) * 64) + lane) * 8];
                acc[ct] = __builtin_amdgcn_mfma_f32_16x16x32_bf16(af, bf, acc[ct], 0, 0, 0);
            }
        }

        if (OUTBF16) {
            __syncthreads();
#pragma unroll
            for (int ct = 0; ct < 8; ++ct) {
#pragma unroll
                for (int r = 0; r < 4; ++r) {
                    int row = wave * 16 + kgrp * 4 + r;
                    int col = ct * 16 + l15;
                    float v = acc[ct][r];
                    if (HASBIAS) v += bias[col];
                    if (RELU)    v = fmaxf(v, 0.f);
                    As[row * H_DIM + ((((col >> 3) ^ (row & 7)) << 3) | (col & 7))] = f2bf(v);
                }
            }
            __syncthreads();
            u16* Out = (u16*)OutV;
            for (int o = threadIdx.x; o < 64 * 16; o += 256) {
                int row = o >> 4, cc = o & 15;
                int grow = tb + row;
                if (grow < M)
                    *(short8*)&Out[(size_t)grow * H_DIM + cc * 8] =
                        *(const short8*)&As[row * H_DIM + ((cc ^ (row & 7)) << 3)];
            }
        } else {
            float* Out = (float*)OutV;
#pragma unroll
            for (int ct = 0; ct < 8; ++ct) {
#pragma unroll
                for (int r = 0; r < 4; ++r) {
                    int grow = tb + wave * 16 + kgrp * 4 + r;
                    if (grow < M) {
                        float v = acc[ct][r];
                        if (HASBIAS) v += bias[ct * 16 + l15];
                        if (RELU)    v = fmaxf(v, 0.f);
                        Out[(size_t)grow * H_DIM + ct * 16 + l15] = v;
                    }
                }
            }
        }
    }
}

// ============================================================
// Fused RGCN conv (v4): R4 structure (128 dsts/block, 8 waves, wave-private
// Abf stripes) + scalar-batched gather: 8 (src,dst) pairs via uniform loads,
// then 8 INDEPENDENT h-row loads in flight (no chained addresses), run-length
// flush on wave-uniform dst change. 2 barriers/relation (Ws only).
// Root folded as 21st relation; epilogue overwrites outb with acc+bias.
// ============================================================
__global__ __launch_bounds__(512, 4)
void rgcn_conv(const u16* __restrict__ h, const u16* __restrict__ Wrel,
               const u16* __restrict__ Wroot, const float* __restrict__ bias,
               const int2* __restrict__ epair, const int* __restrict__ off2,
               float* __restrict__ outb) {
    __shared__ int offs[R_REL][129];
    __shared__ u16 Ws[H_DIM * H_DIM];      // 32 KB, frag-packed W
    __shared__ u16 Abf[128 * H_DIM];       // 32 KB, swizzled A-tile (wave-private stripes)

    const int d0 = blockIdx.x * 128;
    for (int i = threadIdx.x; i < R_REL * 129; i += 512) {
        int r = i / 129, j = i % 129;
        offs[r][j] = off2[r * N_NODES + min(d0 + j, N_NODES)];
    }

    const int lane = threadIdx.x & 63;
    const int wv   = threadIdx.x >> 6;     // 0..7
    const int l15  = lane & 15;
    const int kgrp = lane >> 4;
    const int arow = wv * 16 + l15;
    const u32* h2  = (const u32*)h;
    u32* Ab32 = (u32*)Abf;

    f32x4 acc[8];
#pragma unroll
    for (int i = 0; i < 8; ++i) {
        acc[i][0] = 0.f; acc[i][1] = 0.f; acc[i][2] = 0.f; acc[i][3] = 0.f;
    }

    for (int r = 0; r < R_REL; ++r) {
        __syncthreads();   // MFMA(r-1) done reading Ws; offs ready (r=0)
        const bool active = (offs[r][0] != offs[r][128]);   // block-uniform
        if (active) {
            // stage frag-packed W_r (overlaps the gather below)
            for (int o = threadIdx.x; o < H_DIM * H_DIM / 8; o += 512)
                ((short8*)Ws)[o] = ((const short8*)(Wrel + (size_t)r * H_DIM * H_DIM))[o];

            // zero my stripe (wave-local; MFMA(r-1) of this wave already read it)
#pragma unroll
            for (int i = 0; i < 16; ++i)
                Ab32[(wv * 16 + i) * 64 + lane] = 0u;

            // ---- scalar-batched gather over my contiguous edge range ----
            int estart = __builtin_amdgcn_readfirstlane(offs[r][wv * 16]);
            int eend   = __builtin_amdgcn_readfirstlane(offs[r][wv * 16 + 16]);
            int dcur = -1, cnt = 0;
            float f0 = 0.f, f1 = 0.f;
            for (int e = estart; e < eend; e += 8) {
                int ss[8], dd[8];
#pragma unroll
                for (int j = 0; j < 8; ++j) {
                    int2 pr = epair[min(e + j, eend - 1)];
                    ss[j] = pr.x; dd[j] = pr.y;
                }
                u32 rv[8];
#pragma unroll
                for (int j = 0; j < 8; ++j)
                    rv[j] = h2[(size_t)ss[j] * 64 + lane];   // 8 independent row loads
#pragma unroll
                for (int j = 0; j < 8; ++j) {
                    if (e + j < eend) {                      // wave-uniform guard
                        if (dd[j] != dcur) {                 // wave-uniform branch
                            if (dcur >= 0) {
                                float nm = 1.0f / (float)cnt;
                                int dr = dcur - d0;
                                u32 pk = (u32)f2bf(f0 * nm) | ((u32)f2bf(f1 * nm) << 16);
                                Ab32[dr * 64 + ((((lane >> 2) ^ (dr & 7)) << 2) | (lane & 3))] = pk;
                            }
                            dcur = dd[j]; f0 = 0.f; f1 = 0.f; cnt = 0;
                        }
                        f0 += bf2f((u16)(rv[j] & 0xffff));
                        f1 += bf2f((u16)(rv[j] >> 16));
                        cnt++;
                    }
                }
            }
            if (dcur >= 0) {
                float nm = 1.0f / (float)cnt;
                int dr = dcur - d0;
                u32 pk = (u32)f2bf(f0 * nm) | ((u32)f2bf(f1 * nm) << 16);
                Ab32[dr * 64 + ((((lane >> 2) ^ (dr & 7)) << 2) | (lane & 3))] = pk;
            }
        }
        __syncthreads();   // Ws staged by whole block
        if (active) {
#pragma unroll
            for (int kt = 0; kt < 4; ++kt) {
                short8 af = *(const short8*)&Abf[arow * H_DIM + (((kt * 4 + kgrp) ^ (arow & 7)) * 8)];
#pragma unroll
                for (int ct = 0; ct < 8; ++ct) {
                    short8 bf = *(const short8*)&Ws[(((kt * 8 + ct) * 64) + lane) * 8];
                    acc[ct] = __builtin_amdgcn_mfma_f32_16x16x32_bf16(af, bf, acc[ct], 0, 0, 0);
                }
            }
        }
    }

    // ---- root "relation": dense A = h[d0 .. d0+128) straight from global ----
    __syncthreads();
    for (int o = threadIdx.x; o < H_DIM * H_DIM / 8; o += 512)
        ((short8*)Ws)[o] = ((const short8*)Wroot)[o];
    __syncthreads();
    {
        const int hrow = min(d0 + arow, N_NODES - 1);
#pragma unroll
        for (int kt = 0; kt < 4; ++kt) {
            short8 af = *(const short8*)&h[(size_t)hrow * H_DIM + kt * 32 + kgrp * 8];
#pragma unroll
            for (int ct = 0; ct < 8; ++ct) {
                short8 bf = *(const short8*)&Ws[(((kt * 8 + ct) * 64) + lane) * 8];
                acc[ct] = __builtin_amdgcn_mfma_f32_16x16x32_bf16(af, bf, acc[ct], 0, 0, 0);
            }
        }
    }

    // ---- epilogue: outb = acc + bias (full overwrite) ----
#pragma unroll
    for (int ct = 0; ct < 8; ++ct) {
        float bv = bias[ct * 16 + l15];
#pragma unroll
        for (int rr = 0; rr < 4; ++rr) {
            int grow = d0 + wv * 16 + kgrp * 4 + rr;
            if (grow < N_NODES)
                outb[(size_t)grow * H_DIM + ct * 16 + l15] = acc[ct][rr] + bv;
        }
    }
}

// ============================================================
// BatchNorm + ReLU -> bf16 h
// ============================================================
__global__ void bn_reduce(const float* __restrict__ X, float* __restrict__ sums) {
    int col  = threadIdx.x & 127;
    int half = threadIdx.x >> 7;
    float s = 0.f, ss = 0.f;
    for (int row = blockIdx.x * 2 + half; row < N_NODES; row += gridDim.x * 2) {
        float v = X[(size_t)row * H_DIM + col];
        s += v; ss += v * v;
    }
    atomicAdd(&sums[col], s);
    atomicAdd(&sums[H_DIM + col], ss);
}

__global__ void bn_apply(const float* __restrict__ X, const float* __restrict__ sums,
                         const float* __restrict__ gg, const float* __restrict__ bb,
                         u16* __restrict__ Hout) {
    __shared__ float sc[H_DIM], sh[H_DIM];
    if (threadIdx.x < H_DIM) {
        float mean = sums[threadIdx.x] * (1.0f / N_NODES);
        float var  = sums[H_DIM + threadIdx.x] * (1.0f / N_NODES) - mean * mean;
        float inv  = rsqrtf(var + BN_EPS) * gg[threadIdx.x];
        sc[threadIdx.x] = inv;
        sh[threadIdx.x] = bb[threadIdx.x] - mean * inv;
    }
    __syncthreads();
    int total = N_NODES * (H_DIM / 4);
    for (int idx = blockIdx.x * 256 + threadIdx.x; idx < total; idx += gridDim.x * 256) {
        float4 v = ((const float4*)X)[idx];
        int c = (idx & 31) << 2;
        ushort4 o;
        o.x = f2bf(fmaxf(v.x * sc[c + 0] + sh[c + 0], 0.f));
        o.y = f2bf(fmaxf(v.y * sc[c + 1] + sh[c + 1], 0.f));
        o.z = f2bf(fmaxf(v.z * sc[c + 2] + sh[c + 2], 0.f));
        o.w = f2bf(fmaxf(v.w * sc[c + 3] + sh[c + 3], 0.f));
        ((ushort4*)Hout)[idx] = o;
    }
}

// ============================================================
// Pool + classifier
// ============================================================
__global__ void pool_kernel(const u16* __restrict__ Hf, const int* __restrict__ batch,
                            float* __restrict__ pool, float* __restrict__ pcnt) {
    int col  = threadIdx.x & 127;
    int half = threadIdx.x >> 7;
    int chunk = (N_NODES + gridDim.x - 1) / gridDim.x;
    int start = blockIdx.x * chunk;
    int end   = min(N_NODES, start + chunk);
    int curg = -1;
    float acc = 0.f, c = 0.f;
    for (int row = start + half; row < end; row += 2) {
        int g = batch[row];
        if (g != curg) {
            if (curg >= 0) {
                atomicAdd(&pool[curg * H_DIM + col], acc);
                if (col == 0) atomicAdd(&pcnt[curg], c);
            }
            curg = g; acc = 0.f; c = 0.f;
        }
        acc += bf2f(Hf[(size_t)row * H_DIM + col]);
        c += 1.f;
    }
    if (curg >= 0) {
        atomicAdd(&pool[curg * H_DIM + col], acc);
        if (col == 0) atomicAdd(&pcnt[curg], c);
    }
}

__global__ void logits_kernel(const float* __restrict__ pool, const float* __restrict__ pcnt,
                              const float* __restrict__ w_out, const float* __restrict__ b_out,
                              float* __restrict__ out) {
    int g = blockIdx.x;
    __shared__ float p[H_DIM];
    float cnt = fmaxf(pcnt[g], 1.0f);
    p[threadIdx.x] = pool[g * H_DIM + threadIdx.x] / cnt;
    __syncthreads();
    if (threadIdx.x < C_CLASSES) {
        float acc = b_out[threadIdx.x];
        for (int k = 0; k < H_DIM; ++k)
            acc += p[k] * w_out[k * C_CLASSES + threadIdx.x];
        out[g * C_CLASSES + threadIdx.x] = 1.0f / (1.0f + expf(-acc));
    }
}

// ============================================================
// Host launch
// ============================================================
static inline size_t align256(size_t x) { return (x + 255) & ~(size_t)255; }

extern "C" void kernel_launch(void* const* d_in, const int* in_sizes, int n_in,
                              void* d_out, int out_size, void* d_ws, size_t ws_size,
                              hipStream_t stream) {
    const float* x      = (const float*)d_in[0];
    const int*   ei     = (const int*)d_in[1];
    const int*   et     = (const int*)d_in[2];
    const int*   batch  = (const int*)d_in[3];
    const float* w_in   = (const float*)d_in[4];
    const float* b_in   = (const float*)d_in[5];
    const float* rel_w  = (const float*)d_in[6];
    const float* root_w = (const float*)d_in[7];
    const float* conv_b = (const float*)d_in[8];
    const float* bn_g   = (const float*)d_in[9];
    const float* bn_b   = (const float*)d_in[10];
    const float* w_out  = (const float*)d_in[11];
    const float* b_out  = (const float*)d_in[12];
    float* out = (float*)d_out;

    char* ws = (char*)d_ws;
    size_t off = 0;
    u16*   h_bf  = (u16*)(ws + off);  off += align256((size_t)N_NODES * H_DIM * 2);
    float* outb  = (float*)(ws + off); off += align256((size_t)N_NODES * H_DIM * 4);
    u16*   x_bf  = (u16*)(ws + off);  off += align256((size_t)N_NODES * F_IN * 2);
    int*   off2  = (int*)(ws + off);  off += align256((size_t)(RN + 1) * 4 + 256);
    int*   cur2  = (int*)(ws + off);  off += align256((size_t)RN * 4);
    int2*  e_pair = (int2*)(ws + off); off += align256((size_t)E_EDGES * 8 + 256);
    u16*   wp_in   = (u16*)(ws + off); off += align256((size_t)F_IN * H_DIM * 2);
    u16*   wp_root = (u16*)(ws + off); off += align256((size_t)L_LAYERS * H_DIM * H_DIM * 2);
    u16*   wp_rel  = (u16*)(ws + off); off += align256((size_t)L_LAYERS * R_REL * H_DIM * H_DIM * 2);
    int*   scan_part  = (int*)(ws + off); off += align256(2048 * 4);
    float* bn_sums    = (float*)(ws + off); off += align256(2 * H_DIM * 4);
    float* pool       = (float*)(ws + off); off += align256((size_t)G_GRAPHS * H_DIM * 4);
    float* pcnt       = (float*)(ws + off); off += 256;

    // ---- preprocessing: histogram -> scan -> (rel,dst) counting sort ----
    hipMemsetAsync(cur2, 0, (size_t)RN * 4, stream);    // cur2 doubles as histogram
    count_kernel<<<1024, 256, 0, stream>>>(ei, et, cur2);
    const int NB = (RN + 1023) / 1024;                   // 1954
    scan1_kernel<<<NB, 256, 0, stream>>>(cur2, off2, scan_part, RN);
    scan2_kernel<<<1, 256, 0, stream>>>(scan_part, NB);
    scan3_kernel<<<2048, 256, 0, stream>>>(off2, cur2, scan_part, RN);
    finalize_kernel<<<1, 64, 0, stream>>>(off2);
    bucket_kernel<<<2048, 256, 0, stream>>>(ei, et, cur2, e_pair);

    // ---- convert inputs / pack weights to bf16 ----
    cvt_bf16_kernel<<<2048, 256, 0, stream>>>(x, x_bf, N_NODES * F_IN / 4);
    pack_w<F_IN><<<1, 256, 0, stream>>>(w_in, wp_in);
    pack_w<H_DIM><<<L_LAYERS, 256, 0, stream>>>(root_w, wp_root);
    pack_w<H_DIM><<<L_LAYERS * R_REL, 256, 0, stream>>>(rel_w, wp_rel);

    // ---- input MLP: h = relu(x @ w_in + b_in) -> bf16 ----
    mfma_dense<F_IN, true, true, true><<<dim3(640), 256, 0, stream>>>(
        x_bf, wp_in, b_in, h_bf, N_NODES);

    // ---- RGCN layers (fused conv, scalar-batched gather) ----
    const int CONV_BLOCKS = (N_NODES + 127) / 128;   // 782
    for (int l = 0; l < L_LAYERS; ++l) {
        rgcn_conv<<<dim3(CONV_BLOCKS), 512, 0, stream>>>(
            h_bf, wp_rel + (size_t)l * R_REL * H_DIM * H_DIM,
            wp_root + (size_t)l * H_DIM * H_DIM, conv_b + (size_t)l * H_DIM,
            e_pair, off2, outb);
        hipMemsetAsync(bn_sums, 0, 2 * H_DIM * 4, stream);
        bn_reduce<<<512, 256, 0, stream>>>(outb, bn_sums);
        bn_apply<<<2048, 256, 0, stream>>>(outb, bn_sums,
                                           bn_g + (size_t)l * H_DIM,
                                           bn_b + (size_t)l * H_DIM, h_bf);
    }

    // ---- global mean pool + classifier ----
    hipMemsetAsync(pool, 0, (size_t)G_GRAPHS * H_DIM * 4, stream);
    hipMemsetAsync(pcnt, 0, 256, stream);
    pool_kernel<<<512, 256, 0, stream>>>(h_bf, batch, pool, pcnt);
    logits_kernel<<<G_GRAPHS, 128, 0, stream>>>(pool, pcnt, w_out, b_out, out);
}

// Round 9
// 867.782 us; speedup vs baseline: 4.3241x; 1.0842x over previous
//
#include <hip/hip_runtime.h>

#define N_NODES 100000
#define E_EDGES 1600000
#define F_IN    64
#define H_DIM   128
#define R_REL   20
#define G_GRAPHS 64
#define C_CLASSES 10
#define L_LAYERS 2
#define BN_EPS  1e-5f
#define RN      (R_REL * N_NODES)   // 2,000,000 (rel,dst) bins

typedef unsigned short u16;
typedef unsigned int   u32;
typedef __attribute__((ext_vector_type(8))) short short8;
typedef __attribute__((ext_vector_type(4))) float f32x4;

static __device__ __forceinline__ float bf2f(u16 u) {
    u32 b = ((u32)u) << 16;
    return __builtin_bit_cast(float, b);
}
static __device__ __forceinline__ u16 f2bf(float f) {
    u32 x = __builtin_bit_cast(u32, f);
    u32 r = x + 0x7fff + ((x >> 16) & 1);   // RNE; inputs finite
    return (u16)(r >> 16);
}

// ============================================================
// Edge preprocessing: histogram over (rel,dst), 3-level scan, counting sort
// ============================================================

__global__ void count_kernel(const int* __restrict__ ei, const int* __restrict__ et,
                             int* __restrict__ hist) {
    for (int e = blockIdx.x * blockDim.x + threadIdx.x; e < E_EDGES;
         e += gridDim.x * blockDim.x) {
        int t = et[e];
        int d = ei[E_EDGES + e];
        atomicAdd(&hist[t * N_NODES + d], 1);
    }
}

// exclusive scan, 1024 items / block
__global__ void scan1_kernel(const int* __restrict__ in, int* __restrict__ out,
                             int* __restrict__ part, int n) {
    __shared__ int s[256];
    int t = threadIdx.x;
    int base = blockIdx.x * 1024;
    int v[4]; int sum = 0;
#pragma unroll
    for (int j = 0; j < 4; ++j) {
        int i = base + t * 4 + j;
        v[j] = (i < n) ? in[i] : 0;
        sum += v[j];
    }
    s[t] = sum;
    __syncthreads();
    for (int off = 1; off < 256; off <<= 1) {
        int x = (t >= off) ? s[t - off] : 0;
        __syncthreads();
        s[t] += x;
        __syncthreads();
    }
    if (t == 255) part[blockIdx.x] = s[255];
    int run = s[t] - sum;
#pragma unroll
    for (int j = 0; j < 4; ++j) {
        int i = base + t * 4 + j;
        if (i < n) out[i] = run;
        run += v[j];
    }
}

// exclusive scan of up to 2048 partials in one block (8/thread)
__global__ void scan2_kernel(int* __restrict__ part, int nb) {
    __shared__ int s[256];
    int t = threadIdx.x;
    int loc[8]; int sum = 0;
#pragma unroll
    for (int j = 0; j < 8; ++j) {
        int i = t * 8 + j;
        loc[j] = (i < nb) ? part[i] : 0;
        sum += loc[j];
    }
    s[t] = sum;
    __syncthreads();
    for (int off = 1; off < 256; off <<= 1) {
        int x = (t >= off) ? s[t - off] : 0;
        __syncthreads();
        s[t] += x;
        __syncthreads();
    }
    int run = s[t] - sum;
#pragma unroll
    for (int j = 0; j < 8; ++j) {
        int i = t * 8 + j;
        if (i < nb) part[i] = run;
        run += loc[j];
    }
}

// add block bases; mirror into cur2 (atomic cursors for the sort)
__global__ void scan3_kernel(int* __restrict__ out, int* __restrict__ cur2,
                             const int* __restrict__ part, int n) {
    for (int i = blockIdx.x * blockDim.x + threadIdx.x; i < n;
         i += gridDim.x * blockDim.x) {
        int v = out[i] + part[i >> 10];
        out[i] = v;
        cur2[i] = v;
    }
}

__global__ void finalize_kernel(int* __restrict__ off2) {
    if (threadIdx.x == 0) off2[RN] = E_EDGES;
}

// counting sort into (rel,dst) order; per-edge {src, dst} pair
__global__ void bucket_kernel(const int* __restrict__ ei, const int* __restrict__ et,
                              int* __restrict__ cur2, int2* __restrict__ epair) {
    for (int e = blockIdx.x * blockDim.x + threadIdx.x; e < E_EDGES;
         e += gridDim.x * blockDim.x) {
        int t = et[e];
        int s = ei[e];
        int d = ei[E_EDGES + e];
        int pos = atomicAdd(&cur2[t * N_NODES + d], 1);
        epair[pos] = make_int2(s, d);
    }
}

// ============================================================
// Weight pack: fp32 [K,128] -> bf16 MFMA-frag order (verified R2-R8)
// ============================================================
template<int K>
__global__ void pack_w(const float* __restrict__ W, u16* __restrict__ Wp) {
    const float* w = W + (size_t)blockIdx.x * K * H_DIM;
    u16* p = Wp + (size_t)blockIdx.x * K * H_DIM;
    for (int o = threadIdx.x; o < K * H_DIM; o += blockDim.x) {
        int j  = o & 7;
        int l  = (o >> 3) & 63;
        int ct = (o >> 9) & 7;
        int kt = o >> 12;
        int k  = kt * 32 + (l >> 4) * 8 + j;
        int n  = ct * 16 + (l & 15);
        p[o] = f2bf(w[(size_t)k * H_DIM + n]);
    }
}

__global__ void cvt_bf16_kernel(const float* __restrict__ in, u16* __restrict__ out, int n4) {
    for (int i = blockIdx.x * blockDim.x + threadIdx.x; i < n4;
         i += gridDim.x * blockDim.x) {
        float4 v = ((const float4*)in)[i];
        ushort4 o;
        o.x = f2bf(v.x); o.y = f2bf(v.y); o.z = f2bf(v.z); o.w = f2bf(v.w);
        ((ushort4*)out)[i] = o;
    }
}

// ============================================================
// Dense MFMA GEMM (input MLP) — proven R2-R8 structure
// ============================================================
template<int K, bool RELU, bool HASBIAS, bool OUTBF16>
__global__ __launch_bounds__(256)
void mfma_dense(const u16* __restrict__ A, const u16* __restrict__ Wp,
                const float* __restrict__ bias, void* __restrict__ OutV, int M) {
    constexpr int CH = K / 8;
    __shared__ u16 Ws[K * H_DIM];
    __shared__ u16 As[64 * H_DIM];

    for (int o = threadIdx.x; o < K * H_DIM / 8; o += 256)
        ((short8*)Ws)[o] = ((const short8*)Wp)[o];

    const int lane = threadIdx.x & 63;
    const int wave = threadIdx.x >> 6;
    const int l15  = lane & 15;
    const int kgrp = lane >> 4;
    const int arow = wave * 16 + l15;

    for (int tb = blockIdx.x * 64; tb < M; tb += gridDim.x * 64) {
        __syncthreads();
        for (int o = threadIdx.x; o < 64 * CH; o += 256) {
            int row = o / CH, cc = o % CH;
            int grow = tb + row;
            short8 v = {0,0,0,0,0,0,0,0};
            if (grow < M) v = *(const short8*)&A[(size_t)grow * K + cc * 8];
            *(short8*)&As[row * K + ((cc ^ (row & 7)) * 8)] = v;
        }
        __syncthreads();

        f32x4 acc[8];
#pragma unroll
        for (int i = 0; i < 8; ++i) {
            acc[i][0] = 0.f; acc[i][1] = 0.f; acc[i][2] = 0.f; acc[i][3] = 0.f;
        }
#pragma unroll
        for (int kt = 0; kt < K / 32; ++kt) {
            short8 af = *(const short8*)&As[arow * K + (((kt * 4 + kgrp) ^ (arow & 7)) * 8)];
#pragma unroll
            for (int ct = 0; ct < 8; ++ct) {
                short8 bf = *(const short8*)&Ws[(((kt * 8 + ct) * 64) + lane) * 8];
                acc[ct] = __builtin_amdgcn_mfma_f32_16x16x32_bf16(af, bf, acc[ct], 0, 0, 0);
            }
        }

        if (OUTBF16) {
            __syncthreads();
#pragma unroll
            for (int ct = 0; ct < 8; ++ct) {
#pragma unroll
                for (int r = 0; r < 4; ++r) {
                    int row = wave * 16 + kgrp * 4 + r;
                    int col = ct * 16 + l15;
                    float v = acc[ct][r];
                    if (HASBIAS) v += bias[col];
                    if (RELU)    v = fmaxf(v, 0.f);
                    As[row * H_DIM + ((((col >> 3) ^ (row & 7)) << 3) | (col & 7))] = f2bf(v);
                }
            }
            __syncthreads();
            u16* Out = (u16*)OutV;
            for (int o = threadIdx.x; o < 64 * 16; o += 256) {
                int row = o >> 4, cc = o & 15;
                int grow = tb + row;
                if (grow < M)
                    *(short8*)&Out[(size_t)grow * H_DIM + cc * 8] =
                        *(const short8*)&As[row * H_DIM + ((cc ^ (row & 7)) << 3)];
            }
        } else {
            float* Out = (float*)OutV;
#pragma unroll
            for (int ct = 0; ct < 8; ++ct) {
#pragma unroll
                for (int r = 0; r < 4; ++r) {
                    int grow = tb + wave * 16 + kgrp * 4 + r;
                    if (grow < M) {
                        float v = acc[ct][r];
                        if (HASBIAS) v += bias[ct * 16 + l15];
                        if (RELU)    v = fmaxf(v, 0.f);
                        Out[(size_t)grow * H_DIM + ct * 16 + l15] = v;
                    }
                }
            }
        }
    }
}

// ============================================================
// Fused RGCN conv (v5): R7 structure + (a) 16-deep single-exposure gather,
// (b) cross-relation software pipeline: loads for relation r+1 issued before
// MFMA(r) so L3 latency hides under MFMA + barrier + Ws-stage, (c) BatchNorm
// sum/sumsq fused into the epilogue (replaces bn_reduce dispatch).
// ============================================================
__global__ __launch_bounds__(512, 4)
void rgcn_conv(const u16* __restrict__ h, const u16* __restrict__ Wrel,
               const u16* __restrict__ Wroot, const float* __restrict__ bias,
               const int2* __restrict__ epair, const int* __restrict__ off2,
               float* __restrict__ outb, float* __restrict__ bn_sums) {
    __shared__ int offs[R_REL][129];
    __shared__ u16 Ws[H_DIM * H_DIM];      // 32 KB frag-packed W
    __shared__ u16 Abf[128 * H_DIM];       // 32 KB swizzled A-tile (wave-private stripes)
    __shared__ float bnS[H_DIM], bnSS[H_DIM];

    const int d0 = blockIdx.x * 128;
    for (int i = threadIdx.x; i < R_REL * 129; i += 512) {
        int r = i / 129, j = i % 129;
        offs[r][j] = off2[r * N_NODES + min(d0 + j, N_NODES)];
    }
    if (threadIdx.x < H_DIM) { bnS[threadIdx.x] = 0.f; bnSS[threadIdx.x] = 0.f; }

    const int lane = threadIdx.x & 63;
    const int wv   = threadIdx.x >> 6;     // 0..7
    const int l15  = lane & 15;
    const int kgrp = lane >> 4;
    const int arow = wv * 16 + l15;
    const u32* h2  = (const u32*)h;
    u32* Ab32 = (u32*)Abf;

    f32x4 acc[8];
#pragma unroll
    for (int i = 0; i < 8; ++i) {
        acc[i][0] = 0.f; acc[i][1] = 0.f; acc[i][2] = 0.f; acc[i][3] = 0.f;
    }

    // ---- pipelined gather state (per wave) ----
    int estart = 0, eend = 0;
    int dd[16];
    u32 rv[16];

    auto flushrow = [&](int dcur, int cnt, float f0, float f1) {
        float nm = 1.0f / (float)cnt;
        int dr = dcur - d0;
        u32 pk = (u32)f2bf(f0 * nm) | ((u32)f2bf(f1 * nm) << 16);
        Ab32[dr * 64 + ((((lane >> 2) ^ (dr & 7)) << 2) | (lane & 3))] = pk;
    };

    auto prefetch = [&](int rr) {
        if (rr < R_REL) {
            estart = __builtin_amdgcn_readfirstlane(offs[rr][wv * 16]);
            eend   = __builtin_amdgcn_readfirstlane(offs[rr][wv * 16 + 16]);
            if (eend > estart) {
                const int last = eend - 1;
                int ss[16];
#pragma unroll
                for (int j = 0; j < 16; ++j) {
                    int2 pr = epair[min(estart + j, last)];
                    ss[j] = pr.x; dd[j] = pr.y;
                }
#pragma unroll
                for (int j = 0; j < 16; ++j)
                    rv[j] = h2[(size_t)ss[j] * 64 + lane];
            }
        }
    };

    __syncthreads();      // offs ready
    prefetch(0);          // prologue

    for (int r = 0; r < R_REL; ++r) {
        const bool active = (offs[r][0] != offs[r][128]);   // block-uniform
        if (active) {
            // stage frag-packed W_r
            for (int o = threadIdx.x; o < H_DIM * H_DIM / 8; o += 512)
                ((short8*)Ws)[o] = ((const short8*)(Wrel + (size_t)r * H_DIM * H_DIM))[o];
            // zero my stripe (wave-local)
#pragma unroll
            for (int i = 0; i < 16; ++i)
                Ab32[(wv * 16 + i) * 64 + lane] = 0u;
            // consume prefetched batch (run-length over dst-sorted stream)
            if (eend > estart) {
                int dcur = -1, cnt = 0;
                float f0 = 0.f, f1 = 0.f;
#pragma unroll
                for (int j = 0; j < 16; ++j) {
                    if (estart + j < eend) {                 // wave-uniform
                        if (dd[j] != dcur) {
                            if (dcur >= 0) flushrow(dcur, cnt, f0, f1);
                            dcur = dd[j]; f0 = 0.f; f1 = 0.f; cnt = 0;
                        }
                        f0 += bf2f((u16)(rv[j] & 0xffff));
                        f1 += bf2f((u16)(rv[j] >> 16));
                        cnt++;
                    }
                }
                // overflow batches (rare: segment > 16 edges)
                for (int e = estart + 16; e < eend; e += 16) {
                    const int last = eend - 1;
                    int ss2[16], dd2[16];
                    u32 rv2[16];
#pragma unroll
                    for (int j = 0; j < 16; ++j) {
                        int2 pr = epair[min(e + j, last)];
                        ss2[j] = pr.x; dd2[j] = pr.y;
                    }
#pragma unroll
                    for (int j = 0; j < 16; ++j)
                        rv2[j] = h2[(size_t)ss2[j] * 64 + lane];
#pragma unroll
                    for (int j = 0; j < 16; ++j) {
                        if (e + j < eend) {
                            if (dd2[j] != dcur) {
                                if (dcur >= 0) flushrow(dcur, cnt, f0, f1);
                                dcur = dd2[j]; f0 = 0.f; f1 = 0.f; cnt = 0;
                            }
                            f0 += bf2f((u16)(rv2[j] & 0xffff));
                            f1 += bf2f((u16)(rv2[j] >> 16));
                            cnt++;
                        }
                    }
                }
                if (dcur >= 0) flushrow(dcur, cnt, f0, f1);
            }
        }
        __syncthreads();   // Ws staged + Abf written, before MFMA
        prefetch(r + 1);   // issue next relation's loads; latency hides under MFMA+barrier+stage
        if (active) {
#pragma unroll
            for (int kt = 0; kt < 4; ++kt) {
                short8 af = *(const short8*)&Abf[arow * H_DIM + (((kt * 4 + kgrp) ^ (arow & 7)) * 8)];
#pragma unroll
                for (int ct = 0; ct < 8; ++ct) {
                    short8 bf = *(const short8*)&Ws[(((kt * 8 + ct) * 64) + lane) * 8];
                    acc[ct] = __builtin_amdgcn_mfma_f32_16x16x32_bf16(af, bf, acc[ct], 0, 0, 0);
                }
            }
        }
        __syncthreads();   // all waves done reading Ws before restage
    }

    // ---- root "relation": dense A = h[d0 .. d0+128) straight from global ----
    for (int o = threadIdx.x; o < H_DIM * H_DIM / 8; o += 512)
        ((short8*)Ws)[o] = ((const short8*)Wroot)[o];
    __syncthreads();
    {
        const int hrow = min(d0 + arow, N_NODES - 1);
#pragma unroll
        for (int kt = 0; kt < 4; ++kt) {
            short8 af = *(const short8*)&h[(size_t)hrow * H_DIM + kt * 32 + kgrp * 8];
#pragma unroll
            for (int ct = 0; ct < 8; ++ct) {
                short8 bf = *(const short8*)&Ws[(((kt * 8 + ct) * 64) + lane) * 8];
                acc[ct] = __builtin_amdgcn_mfma_f32_16x16x32_bf16(af, bf, acc[ct], 0, 0, 0);
            }
        }
    }

    // ---- epilogue: outb = acc + bias; fused BN sum/sumsq ----
#pragma unroll
    for (int ct = 0; ct < 8; ++ct) {
        float bv = bias[ct * 16 + l15];
        float sl = 0.f, sq = 0.f;
#pragma unroll
        for (int rr = 0; rr < 4; ++rr) {
            int grow = d0 + wv * 16 + kgrp * 4 + rr;
            if (grow < N_NODES) {
                float v = acc[ct][rr] + bv;
                outb[(size_t)grow * H_DIM + ct * 16 + l15] = v;
                sl += v;
                sq += v * v;
            }
        }
        // reduce over kgrp (lanes with same l15): XOR 16, 32
        sl += __shfl_xor(sl, 16); sl += __shfl_xor(sl, 32);
        sq += __shfl_xor(sq, 16); sq += __shfl_xor(sq, 32);
        if (kgrp == 0) {
            atomicAdd(&bnS[ct * 16 + l15], sl);
            atomicAdd(&bnSS[ct * 16 + l15], sq);
        }
    }
    __syncthreads();
    if (threadIdx.x < H_DIM) {
        atomicAdd(&bn_sums[threadIdx.x], bnS[threadIdx.x]);
        atomicAdd(&bn_sums[H_DIM + threadIdx.x], bnSS[threadIdx.x]);
    }
}

// ============================================================
// BatchNorm apply + ReLU -> bf16 h
// ============================================================
__global__ void bn_apply(const float* __restrict__ X, const float* __restrict__ sums,
                         const float* __restrict__ gg, const float* __restrict__ bb,
                         u16* __restrict__ Hout) {
    __shared__ float sc[H_DIM], sh[H_DIM];
    if (threadIdx.x < H_DIM) {
        float mean = sums[threadIdx.x] * (1.0f / N_NODES);
        float var  = sums[H_DIM + threadIdx.x] * (1.0f / N_NODES) - mean * mean;
        float inv  = rsqrtf(var + BN_EPS) * gg[threadIdx.x];
        sc[threadIdx.x] = inv;
        sh[threadIdx.x] = bb[threadIdx.x] - mean * inv;
    }
    __syncthreads();
    int total = N_NODES * (H_DIM / 4);
    for (int idx = blockIdx.x * 256 + threadIdx.x; idx < total; idx += gridDim.x * 256) {
        float4 v = ((const float4*)X)[idx];
        int c = (idx & 31) << 2;
        ushort4 o;
        o.x = f2bf(fmaxf(v.x * sc[c + 0] + sh[c + 0], 0.f));
        o.y = f2bf(fmaxf(v.y * sc[c + 1] + sh[c + 1], 0.f));
        o.z = f2bf(fmaxf(v.z * sc[c + 2] + sh[c + 2], 0.f));
        o.w = f2bf(fmaxf(v.w * sc[c + 3] + sh[c + 3], 0.f));
        ((ushort4*)Hout)[idx] = o;
    }
}

// ============================================================
// Pool + classifier
// ============================================================
__global__ void pool_kernel(const u16* __restrict__ Hf, const int* __restrict__ batch,
                            float* __restrict__ pool, float* __restrict__ pcnt) {
    int col  = threadIdx.x & 127;
    int half = threadIdx.x >> 7;
    int chunk = (N_NODES + gridDim.x - 1) / gridDim.x;
    int start = blockIdx.x * chunk;
    int end   = min(N_NODES, start + chunk);
    int curg = -1;
    float acc = 0.f, c = 0.f;
    for (int row = start + half; row < end; row += 2) {
        int g = batch[row];
        if (g != curg) {
            if (curg >= 0) {
                atomicAdd(&pool[curg * H_DIM + col], acc);
                if (col == 0) atomicAdd(&pcnt[curg], c);
            }
            curg = g; acc = 0.f; c = 0.f;
        }
        acc += bf2f(Hf[(size_t)row * H_DIM + col]);
        c += 1.f;
    }
    if (curg >= 0) {
        atomicAdd(&pool[curg * H_DIM + col], acc);
        if (col == 0) atomicAdd(&pcnt[curg], c);
    }
}

__global__ void logits_kernel(const float* __restrict__ pool, const float* __restrict__ pcnt,
                              const float* __restrict__ w_out, const float* __restrict__ b_out,
                              float* __restrict__ out) {
    int g = blockIdx.x;
    __shared__ float p[H_DIM];
    float cnt = fmaxf(pcnt[g], 1.0f);
    p[threadIdx.x] = pool[g * H_DIM + threadIdx.x] / cnt;
    __syncthreads();
    if (threadIdx.x < C_CLASSES) {
        float acc = b_out[threadIdx.x];
        for (int k = 0; k < H_DIM; ++k)
            acc += p[k] * w_out[k * C_CLASSES + threadIdx.x];
        out[g * C_CLASSES + threadIdx.x] = 1.0f / (1.0f + expf(-acc));
    }
}

// ============================================================
// Host launch
// ============================================================
static inline size_t align256(size_t x) { return (x + 255) & ~(size_t)255; }

extern "C" void kernel_launch(void* const* d_in, const int* in_sizes, int n_in,
                              void* d_out, int out_size, void* d_ws, size_t ws_size,
                              hipStream_t stream) {
    const float* x      = (const float*)d_in[0];
    const int*   ei     = (const int*)d_in[1];
    const int*   et     = (const int*)d_in[2];
    const int*   batch  = (const int*)d_in[3];
    const float* w_in   = (const float*)d_in[4];
    const float* b_in   = (const float*)d_in[5];
    const float* rel_w  = (const float*)d_in[6];
    const float* root_w = (const float*)d_in[7];
    const float* conv_b = (const float*)d_in[8];
    const float* bn_g   = (const float*)d_in[9];
    const float* bn_b   = (const float*)d_in[10];
    const float* w_out  = (const float*)d_in[11];
    const float* b_out  = (const float*)d_in[12];
    float* out = (float*)d_out;

    char* ws = (char*)d_ws;
    size_t off = 0;
    u16*   h_bf  = (u16*)(ws + off);  off += align256((size_t)N_NODES * H_DIM * 2);
    float* outb  = (float*)(ws + off); off += align256((size_t)N_NODES * H_DIM * 4);
    u16*   x_bf  = (u16*)(ws + off);  off += align256((size_t)N_NODES * F_IN * 2);
    int*   off2  = (int*)(ws + off);  off += align256((size_t)(RN + 1) * 4 + 256);
    int*   cur2  = (int*)(ws + off);  off += align256((size_t)RN * 4);
    int2*  e_pair = (int2*)(ws + off); off += align256((size_t)E_EDGES * 8 + 256);
    u16*   wp_in   = (u16*)(ws + off); off += align256((size_t)F_IN * H_DIM * 2);
    u16*   wp_root = (u16*)(ws + off); off += align256((size_t)L_LAYERS * H_DIM * H_DIM * 2);
    u16*   wp_rel  = (u16*)(ws + off); off += align256((size_t)L_LAYERS * R_REL * H_DIM * H_DIM * 2);
    int*   scan_part  = (int*)(ws + off); off += align256(2048 * 4);
    float* bn_sums    = (float*)(ws + off); off += align256(2 * H_DIM * 4);
    float* pool       = (float*)(ws + off); off += align256((size_t)G_GRAPHS * H_DIM * 4);
    float* pcnt       = (float*)(ws + off); off += 256;

    // ---- preprocessing: histogram -> scan -> (rel,dst) counting sort ----
    hipMemsetAsync(cur2, 0, (size_t)RN * 4, stream);    // cur2 doubles as histogram
    count_kernel<<<1024, 256, 0, stream>>>(ei, et, cur2);
    const int NB = (RN + 1023) / 1024;                   // 1954
    scan1_kernel<<<NB, 256, 0, stream>>>(cur2, off2, scan_part, RN);
    scan2_kernel<<<1, 256, 0, stream>>>(scan_part, NB);
    scan3_kernel<<<2048, 256, 0, stream>>>(off2, cur2, scan_part, RN);
    finalize_kernel<<<1, 64, 0, stream>>>(off2);
    bucket_kernel<<<2048, 256, 0, stream>>>(ei, et, cur2, e_pair);

    // ---- convert inputs / pack weights to bf16 ----
    cvt_bf16_kernel<<<2048, 256, 0, stream>>>(x, x_bf, N_NODES * F_IN / 4);
    pack_w<F_IN><<<1, 256, 0, stream>>>(w_in, wp_in);
    pack_w<H_DIM><<<L_LAYERS, 256, 0, stream>>>(root_w, wp_root);
    pack_w<H_DIM><<<L_LAYERS * R_REL, 256, 0, stream>>>(rel_w, wp_rel);

    // ---- input MLP: h = relu(x @ w_in + b_in) -> bf16 ----
    mfma_dense<F_IN, true, true, true><<<dim3(640), 256, 0, stream>>>(
        x_bf, wp_in, b_in, h_bf, N_NODES);

    // ---- RGCN layers (pipelined fused conv, BN stats fused in epilogue) ----
    const int CONV_BLOCKS = (N_NODES + 127) / 128;   // 782
    for (int l = 0; l < L_LAYERS; ++l) {
        hipMemsetAsync(bn_sums, 0, 2 * H_DIM * 4, stream);
        rgcn_conv<<<dim3(CONV_BLOCKS), 512, 0, stream>>>(
            h_bf, wp_rel + (size_t)l * R_REL * H_DIM * H_DIM,
            wp_root + (size_t)l * H_DIM * H_DIM, conv_b + (size_t)l * H_DIM,
            e_pair, off2, outb, bn_sums);
        bn_apply<<<2048, 256, 0, stream>>>(outb, bn_sums,
                                           bn_g + (size_t)l * H_DIM,
                                           bn_b + (size_t)l * H_DIM, h_bf);
    }

    // ---- global mean pool + classifier ----
    hipMemsetAsync(pool, 0, (size_t)G_GRAPHS * H_DIM * 4, stream);
    hipMemsetAsync(pcnt, 0, 256, stream);
    pool_kernel<<<512, 256, 0, stream>>>(h_bf, batch, pool, pcnt);
    logits_kernel<<<G_GRAPHS, 128, 0, stream>>>(pool, pcnt, w_out, b_out, out);
}

// Round 10
// 817.576 us; speedup vs baseline: 4.5896x; 1.0614x over previous
//
#include <hip/hip_runtime.h>

#define N_NODES 100000
#define E_EDGES 1600000
#define F_IN    64
#define H_DIM   128
#define R_REL   20
#define G_GRAPHS 64
#define C_CLASSES 10
#define L_LAYERS 2
#define BN_EPS  1e-5f
#define RN      (R_REL * N_NODES)   // 2,000,000 (rel,dst) bins

typedef unsigned short u16;
typedef unsigned int   u32;
typedef __attribute__((ext_vector_type(8))) short short8;
typedef __attribute__((ext_vector_type(4))) float f32x4;

static __device__ __forceinline__ float bf2f(u16 u) {
    u32 b = ((u32)u) << 16;
    return __builtin_bit_cast(float, b);
}
static __device__ __forceinline__ u16 f2bf(float f) {
    u32 x = __builtin_bit_cast(u32, f);
    u32 r = x + 0x7fff + ((x >> 16) & 1);   // RNE; inputs finite
    return (u16)(r >> 16);
}

// ============================================================
// Edge preprocessing: histogram over (rel,dst), 3-level scan, counting sort
// ============================================================

__global__ void count_kernel(const int* __restrict__ ei, const int* __restrict__ et,
                             int* __restrict__ hist) {
    for (int e = blockIdx.x * blockDim.x + threadIdx.x; e < E_EDGES;
         e += gridDim.x * blockDim.x) {
        int t = et[e];
        int d = ei[E_EDGES + e];
        atomicAdd(&hist[t * N_NODES + d], 1);
    }
}

// exclusive scan, 1024 items / block
__global__ void scan1_kernel(const int* __restrict__ in, int* __restrict__ out,
                             int* __restrict__ part, int n) {
    __shared__ int s[256];
    int t = threadIdx.x;
    int base = blockIdx.x * 1024;
    int v[4]; int sum = 0;
#pragma unroll
    for (int j = 0; j < 4; ++j) {
        int i = base + t * 4 + j;
        v[j] = (i < n) ? in[i] : 0;
        sum += v[j];
    }
    s[t] = sum;
    __syncthreads();
    for (int off = 1; off < 256; off <<= 1) {
        int x = (t >= off) ? s[t - off] : 0;
        __syncthreads();
        s[t] += x;
        __syncthreads();
    }
    if (t == 255) part[blockIdx.x] = s[255];
    int run = s[t] - sum;
#pragma unroll
    for (int j = 0; j < 4; ++j) {
        int i = base + t * 4 + j;
        if (i < n) out[i] = run;
        run += v[j];
    }
}

// exclusive scan of up to 2048 partials in one block (8/thread)
__global__ void scan2_kernel(int* __restrict__ part, int nb) {
    __shared__ int s[256];
    int t = threadIdx.x;
    int loc[8]; int sum = 0;
#pragma unroll
    for (int j = 0; j < 8; ++j) {
        int i = t * 8 + j;
        loc[j] = (i < nb) ? part[i] : 0;
        sum += loc[j];
    }
    s[t] = sum;
    __syncthreads();
    for (int off = 1; off < 256; off <<= 1) {
        int x = (t >= off) ? s[t - off] : 0;
        __syncthreads();
        s[t] += x;
        __syncthreads();
    }
    int run = s[t] - sum;
#pragma unroll
    for (int j = 0; j < 8; ++j) {
        int i = t * 8 + j;
        if (i < nb) part[i] = run;
        run += loc[j];
    }
}

// add block bases; mirror into cur2 (atomic cursors for the sort)
__global__ void scan3_kernel(int* __restrict__ out, int* __restrict__ cur2,
                             const int* __restrict__ part, int n) {
    for (int i = blockIdx.x * blockDim.x + threadIdx.x; i < n;
         i += gridDim.x * blockDim.x) {
        int v = out[i] + part[i >> 10];
        out[i] = v;
        cur2[i] = v;
    }
}

__global__ void finalize_kernel(int* __restrict__ off2) {
    if (threadIdx.x == 0) off2[RN] = E_EDGES;
}

// counting sort into (rel,dst) order; per-edge {src, dst} pair
__global__ void bucket_kernel(const int* __restrict__ ei, const int* __restrict__ et,
                              int* __restrict__ cur2, int2* __restrict__ epair) {
    for (int e = blockIdx.x * blockDim.x + threadIdx.x; e < E_EDGES;
         e += gridDim.x * blockDim.x) {
        int t = et[e];
        int s = ei[e];
        int d = ei[E_EDGES + e];
        int pos = atomicAdd(&cur2[t * N_NODES + d], 1);
        epair[pos] = make_int2(s, d);
    }
}

// ============================================================
// Weight pack: fp32 [K,128] -> bf16 MFMA-frag order (verified R2-R9)
// ============================================================
template<int K>
__global__ void pack_w(const float* __restrict__ W, u16* __restrict__ Wp) {
    const float* w = W + (size_t)blockIdx.x * K * H_DIM;
    u16* p = Wp + (size_t)blockIdx.x * K * H_DIM;
    for (int o = threadIdx.x; o < K * H_DIM; o += blockDim.x) {
        int j  = o & 7;
        int l  = (o >> 3) & 63;
        int ct = (o >> 9) & 7;
        int kt = o >> 12;
        int k  = kt * 32 + (l >> 4) * 8 + j;
        int n  = ct * 16 + (l & 15);
        p[o] = f2bf(w[(size_t)k * H_DIM + n]);
    }
}

__global__ void cvt_bf16_kernel(const float* __restrict__ in, u16* __restrict__ out, int n4) {
    for (int i = blockIdx.x * blockDim.x + threadIdx.x; i < n4;
         i += gridDim.x * blockDim.x) {
        float4 v = ((const float4*)in)[i];
        ushort4 o;
        o.x = f2bf(v.x); o.y = f2bf(v.y); o.z = f2bf(v.z); o.w = f2bf(v.w);
        ((ushort4*)out)[i] = o;
    }
}

// ============================================================
// Dense MFMA GEMM (input MLP) — proven R2-R9 structure
// ============================================================
template<int K, bool RELU, bool HASBIAS, bool OUTBF16>
__global__ __launch_bounds__(256)
void mfma_dense(const u16* __restrict__ A, const u16* __restrict__ Wp,
                const float* __restrict__ bias, void* __restrict__ OutV, int M) {
    constexpr int CH = K / 8;
    __shared__ u16 Ws[K * H_DIM];
    __shared__ u16 As[64 * H_DIM];

    for (int o = threadIdx.x; o < K * H_DIM / 8; o += 256)
        ((short8*)Ws)[o] = ((const short8*)Wp)[o];

    const int lane = threadIdx.x & 63;
    const int wave = threadIdx.x >> 6;
    const int l15  = lane & 15;
    const int kgrp = lane >> 4;
    const int arow = wave * 16 + l15;

    for (int tb = blockIdx.x * 64; tb < M; tb += gridDim.x * 64) {
        __syncthreads();
        for (int o = threadIdx.x; o < 64 * CH; o += 256) {
            int row = o / CH, cc = o % CH;
            int grow = tb + row;
            short8 v = {0,0,0,0,0,0,0,0};
            if (grow < M) v = *(const short8*)&A[(size_t)grow * K + cc * 8];
            *(short8*)&As[row * K + ((cc ^ (row & 7)) * 8)] = v;
        }
        __syncthreads();

        f32x4 acc[8];
#pragma unroll
        for (int i = 0; i < 8; ++i) {
            acc[i][0] = 0.f; acc[i][1] = 0.f; acc[i][2] = 0.f; acc[i][3] = 0.f;
        }
#pragma unroll
        for (int kt = 0; kt < K / 32; ++kt) {
            short8 af = *(const short8*)&As[arow * K + (((kt * 4 + kgrp) ^ (arow & 7)) * 8)];
#pragma unroll
            for (int ct = 0; ct < 8; ++ct) {
                short8 bf = *(const short8*)&Ws[(((kt * 8 + ct) * 64) + lane) * 8];
                acc[ct] = __builtin_amdgcn_mfma_f32_16x16x32_bf16(af, bf, acc[ct], 0, 0, 0);
            }
        }

        if (OUTBF16) {
            __syncthreads();
#pragma unroll
            for (int ct = 0; ct < 8; ++ct) {
#pragma unroll
                for (int r = 0; r < 4; ++r) {
                    int row = wave * 16 + kgrp * 4 + r;
                    int col = ct * 16 + l15;
                    float v = acc[ct][r];
                    if (HASBIAS) v += bias[col];
                    if (RELU)    v = fmaxf(v, 0.f);
                    As[row * H_DIM + ((((col >> 3) ^ (row & 7)) << 3) | (col & 7))] = f2bf(v);
                }
            }
            __syncthreads();
            u16* Out = (u16*)OutV;
            for (int o = threadIdx.x; o < 64 * 16; o += 256) {
                int row = o >> 4, cc = o & 15;
                int grow = tb + row;
                if (grow < M)
                    *(short8*)&Out[(size_t)grow * H_DIM + cc * 8] =
                        *(const short8*)&As[row * H_DIM + ((cc ^ (row & 7)) << 3)];
            }
        } else {
            float* Out = (float*)OutV;
#pragma unroll
            for (int ct = 0; ct < 8; ++ct) {
#pragma unroll
                for (int r = 0; r < 4; ++r) {
                    int grow = tb + wave * 16 + kgrp * 4 + r;
                    if (grow < M) {
                        float v = acc[ct][r];
                        if (HASBIAS) v += bias[ct * 16 + l15];
                        if (RELU)    v = fmaxf(v, 0.f);
                        Out[(size_t)grow * H_DIM + ct * 16 + l15] = v;
                    }
                }
            }
        }
    }
}

// ============================================================
// Fused RGCN conv (v6): BARRIER-FREE relation loop. Block = 64 dsts,
// 4 waves, each wave owns a private 16-row Abf stripe. B-fragments are
// read DIRECTLY FROM GLOBAL (frag-packed weights, 1.25 MB, L2-resident,
// 1KB coalesced per load) -> no Ws LDS, no cross-wave coupling, waves
// free-run across relations; latency hidden by TLP (16+ waves/CU).
// Per-wave skip of empty segments. BN sum/sumsq fused in epilogue.
// ============================================================
__global__ __launch_bounds__(256, 4)
void rgcn_conv(const u16* __restrict__ h, const u16* __restrict__ Wrel,
               const u16* __restrict__ Wroot, const float* __restrict__ bias,
               const int2* __restrict__ epair, const int* __restrict__ off2,
               float* __restrict__ outb, float* __restrict__ bn_sums) {
    __shared__ int offs[R_REL][65];
    __shared__ u16 Abf[64 * H_DIM];        // 16 KB; wave-private 16-row stripes
    __shared__ float bnS[H_DIM], bnSS[H_DIM];

    const int d0 = blockIdx.x * 64;
    for (int i = threadIdx.x; i < R_REL * 65; i += 256) {
        int r = i / 65, j = i % 65;
        offs[r][j] = off2[r * N_NODES + min(d0 + j, N_NODES)];
    }
    if (threadIdx.x < H_DIM) { bnS[threadIdx.x] = 0.f; bnSS[threadIdx.x] = 0.f; }

    const int lane = threadIdx.x & 63;
    const int wv   = threadIdx.x >> 6;     // 0..3
    const int l15  = lane & 15;
    const int kgrp = lane >> 4;
    const int arow = wv * 16 + l15;        // 0..63
    const u32* h2  = (const u32*)h;
    u32* Ab32 = (u32*)Abf;

    f32x4 acc[8];
#pragma unroll
    for (int i = 0; i < 8; ++i) {
        acc[i][0] = 0.f; acc[i][1] = 0.f; acc[i][2] = 0.f; acc[i][3] = 0.f;
    }

    auto flushrow = [&](int dcur, int cnt, float f0, float f1) {
        float nm = 1.0f / (float)cnt;
        int dr = dcur - d0;
        u32 pk = (u32)f2bf(f0 * nm) | ((u32)f2bf(f1 * nm) << 16);
        Ab32[dr * 64 + ((((lane >> 2) ^ (dr & 7)) << 2) | (lane & 3))] = pk;
    };

    __syncthreads();      // offs + bnS init visible (only barrier before epilogue)

    for (int r = 0; r < R_REL; ++r) {
        const int estart = __builtin_amdgcn_readfirstlane(offs[r][wv * 16]);
        const int eend   = __builtin_amdgcn_readfirstlane(offs[r][wv * 16 + 16]);
        if (eend <= estart) continue;      // wave-private skip (no barriers to honor)

        // zero my stripe (wave-local)
#pragma unroll
        for (int i = 0; i < 16; ++i)
            Ab32[(wv * 16 + i) * 64 + lane] = 0u;

        // ---- 16-deep batched gather + run-length flush ----
        {
            const int last = eend - 1;
            int ss[16], dd[16];
            u32 rv[16];
#pragma unroll
            for (int j = 0; j < 16; ++j) {
                int2 pr = epair[min(estart + j, last)];
                ss[j] = pr.x; dd[j] = pr.y;
            }
#pragma unroll
            for (int j = 0; j < 16; ++j)
                rv[j] = h2[(size_t)ss[j] * 64 + lane];

            int dcur = -1, cnt = 0;
            float f0 = 0.f, f1 = 0.f;
#pragma unroll
            for (int j = 0; j < 16; ++j) {
                if (estart + j < eend) {                 // wave-uniform
                    if (dd[j] != dcur) {
                        if (dcur >= 0) flushrow(dcur, cnt, f0, f1);
                        dcur = dd[j]; f0 = 0.f; f1 = 0.f; cnt = 0;
                    }
                    f0 += bf2f((u16)(rv[j] & 0xffff));
                    f1 += bf2f((u16)(rv[j] >> 16));
                    cnt++;
                }
            }
            // overflow batches (segment > 16 edges)
            for (int e = estart + 16; e < eend; e += 16) {
                int ss2[16], dd2[16];
                u32 rv2[16];
#pragma unroll
                for (int j = 0; j < 16; ++j) {
                    int2 pr = epair[min(e + j, last)];
                    ss2[j] = pr.x; dd2[j] = pr.y;
                }
#pragma unroll
                for (int j = 0; j < 16; ++j)
                    rv2[j] = h2[(size_t)ss2[j] * 64 + lane];
#pragma unroll
                for (int j = 0; j < 16; ++j) {
                    if (e + j < eend) {
                        if (dd2[j] != dcur) {
                            if (dcur >= 0) flushrow(dcur, cnt, f0, f1);
                            dcur = dd2[j]; f0 = 0.f; f1 = 0.f; cnt = 0;
                        }
                        f0 += bf2f((u16)(rv2[j] & 0xffff));
                        f1 += bf2f((u16)(rv2[j] >> 16));
                        cnt++;
                    }
                }
            }
            if (dcur >= 0) flushrow(dcur, cnt, f0, f1);
        }

        // ---- MFMA: A from my LDS stripe, B direct from global (L2-hot) ----
        const u16* Wr = Wrel + (size_t)r * H_DIM * H_DIM;
#pragma unroll
        for (int kt = 0; kt < 4; ++kt) {
            short8 af = *(const short8*)&Abf[arow * H_DIM + (((kt * 4 + kgrp) ^ (arow & 7)) * 8)];
#pragma unroll
            for (int ct = 0; ct < 8; ++ct) {
                short8 bf = *(const short8*)&Wr[(((kt * 8 + ct) * 64) + lane) * 8];
                acc[ct] = __builtin_amdgcn_mfma_f32_16x16x32_bf16(af, bf, acc[ct], 0, 0, 0);
            }
        }
    }

    // ---- root "relation": dense A = h rows direct from global ----
    {
        const int hrow = min(d0 + arow, N_NODES - 1);
#pragma unroll
        for (int kt = 0; kt < 4; ++kt) {
            short8 af = *(const short8*)&h[(size_t)hrow * H_DIM + kt * 32 + kgrp * 8];
#pragma unroll
            for (int ct = 0; ct < 8; ++ct) {
                short8 bf = *(const short8*)&Wroot[(((kt * 8 + ct) * 64) + lane) * 8];
                acc[ct] = __builtin_amdgcn_mfma_f32_16x16x32_bf16(af, bf, acc[ct], 0, 0, 0);
            }
        }
    }

    // ---- epilogue: outb = acc + bias; fused BN sum/sumsq ----
#pragma unroll
    for (int ct = 0; ct < 8; ++ct) {
        float bv = bias[ct * 16 + l15];
        float sl = 0.f, sq = 0.f;
#pragma unroll
        for (int rr = 0; rr < 4; ++rr) {
            int grow = d0 + wv * 16 + kgrp * 4 + rr;
            if (grow < N_NODES) {
                float v = acc[ct][rr] + bv;
                outb[(size_t)grow * H_DIM + ct * 16 + l15] = v;
                sl += v;
                sq += v * v;
            }
        }
        sl += __shfl_xor(sl, 16); sl += __shfl_xor(sl, 32);
        sq += __shfl_xor(sq, 16); sq += __shfl_xor(sq, 32);
        if (kgrp == 0) {
            atomicAdd(&bnS[ct * 16 + l15], sl);
            atomicAdd(&bnSS[ct * 16 + l15], sq);
        }
    }
    __syncthreads();
    if (threadIdx.x < H_DIM) {
        atomicAdd(&bn_sums[threadIdx.x], bnS[threadIdx.x]);
        atomicAdd(&bn_sums[H_DIM + threadIdx.x], bnSS[threadIdx.x]);
    }
}

// ============================================================
// BatchNorm apply + ReLU -> bf16 h
// ============================================================
__global__ void bn_apply(const float* __restrict__ X, const float* __restrict__ sums,
                         const float* __restrict__ gg, const float* __restrict__ bb,
                         u16* __restrict__ Hout) {
    __shared__ float sc[H_DIM], sh[H_DIM];
    if (threadIdx.x < H_DIM) {
        float mean = sums[threadIdx.x] * (1.0f / N_NODES);
        float var  = sums[H_DIM + threadIdx.x] * (1.0f / N_NODES) - mean * mean;
        float inv  = rsqrtf(var + BN_EPS) * gg[threadIdx.x];
        sc[threadIdx.x] = inv;
        sh[threadIdx.x] = bb[threadIdx.x] - mean * inv;
    }
    __syncthreads();
    int total = N_NODES * (H_DIM / 4);
    for (int idx = blockIdx.x * 256 + threadIdx.x; idx < total; idx += gridDim.x * 256) {
        float4 v = ((const float4*)X)[idx];
        int c = (idx & 31) << 2;
        ushort4 o;
        o.x = f2bf(fmaxf(v.x * sc[c + 0] + sh[c + 0], 0.f));
        o.y = f2bf(fmaxf(v.y * sc[c + 1] + sh[c + 1], 0.f));
        o.z = f2bf(fmaxf(v.z * sc[c + 2] + sh[c + 2], 0.f));
        o.w = f2bf(fmaxf(v.w * sc[c + 3] + sh[c + 3], 0.f));
        ((ushort4*)Hout)[idx] = o;
    }
}

// ============================================================
// Pool + classifier
// ============================================================
__global__ void pool_kernel(const u16* __restrict__ Hf, const int* __restrict__ batch,
                            float* __restrict__ pool, float* __restrict__ pcnt) {
    int col  = threadIdx.x & 127;
    int half = threadIdx.x >> 7;
    int chunk = (N_NODES + gridDim.x - 1) / gridDim.x;
    int start = blockIdx.x * chunk;
    int end   = min(N_NODES, start + chunk);
    int curg = -1;
    float acc = 0.f, c = 0.f;
    for (int row = start + half; row < end; row += 2) {
        int g = batch[row];
        if (g != curg) {
            if (curg >= 0) {
                atomicAdd(&pool[curg * H_DIM + col], acc);
                if (col == 0) atomicAdd(&pcnt[curg], c);
            }
            curg = g; acc = 0.f; c = 0.f;
        }
        acc += bf2f(Hf[(size_t)row * H_DIM + col]);
        c += 1.f;
    }
    if (curg >= 0) {
        atomicAdd(&pool[curg * H_DIM + col], acc);
        if (col == 0) atomicAdd(&pcnt[curg], c);
    }
}

__global__ void logits_kernel(const float* __restrict__ pool, const float* __restrict__ pcnt,
                              const float* __restrict__ w_out, const float* __restrict__ b_out,
                              float* __restrict__ out) {
    int g = blockIdx.x;
    __shared__ float p[H_DIM];
    float cnt = fmaxf(pcnt[g], 1.0f);
    p[threadIdx.x] = pool[g * H_DIM + threadIdx.x] / cnt;
    __syncthreads();
    if (threadIdx.x < C_CLASSES) {
        float acc = b_out[threadIdx.x];
        for (int k = 0; k < H_DIM; ++k)
            acc += p[k] * w_out[k * C_CLASSES + threadIdx.x];
        out[g * C_CLASSES + threadIdx.x] = 1.0f / (1.0f + expf(-acc));
    }
}

// ============================================================
// Host launch
// ============================================================
static inline size_t align256(size_t x) { return (x + 255) & ~(size_t)255; }

extern "C" void kernel_launch(void* const* d_in, const int* in_sizes, int n_in,
                              void* d_out, int out_size, void* d_ws, size_t ws_size,
                              hipStream_t stream) {
    const float* x      = (const float*)d_in[0];
    const int*   ei     = (const int*)d_in[1];
    const int*   et     = (const int*)d_in[2];
    const int*   batch  = (const int*)d_in[3];
    const float* w_in   = (const float*)d_in[4];
    const float* b_in   = (const float*)d_in[5];
    const float* rel_w  = (const float*)d_in[6];
    const float* root_w = (const float*)d_in[7];
    const float* conv_b = (const float*)d_in[8];
    const float* bn_g   = (const float*)d_in[9];
    const float* bn_b   = (const float*)d_in[10];
    const float* w_out  = (const float*)d_in[11];
    const float* b_out  = (const float*)d_in[12];
    float* out = (float*)d_out;

    char* ws = (char*)d_ws;
    size_t off = 0;
    u16*   h_bf  = (u16*)(ws + off);  off += align256((size_t)N_NODES * H_DIM * 2);
    float* outb  = (float*)(ws + off); off += align256((size_t)N_NODES * H_DIM * 4);
    u16*   x_bf  = (u16*)(ws + off);  off += align256((size_t)N_NODES * F_IN * 2);
    int*   off2  = (int*)(ws + off);  off += align256((size_t)(RN + 1) * 4 + 256);
    int*   cur2  = (int*)(ws + off);  off += align256((size_t)RN * 4);
    int2*  e_pair = (int2*)(ws + off); off += align256((size_t)E_EDGES * 8 + 256);
    u16*   wp_in   = (u16*)(ws + off); off += align256((size_t)F_IN * H_DIM * 2);
    u16*   wp_root = (u16*)(ws + off); off += align256((size_t)L_LAYERS * H_DIM * H_DIM * 2);
    u16*   wp_rel  = (u16*)(ws + off); off += align256((size_t)L_LAYERS * R_REL * H_DIM * H_DIM * 2);
    int*   scan_part  = (int*)(ws + off); off += align256(2048 * 4);
    float* bn_sums    = (float*)(ws + off); off += align256(2 * H_DIM * 4);
    float* pool       = (float*)(ws + off); off += align256((size_t)G_GRAPHS * H_DIM * 4);
    float* pcnt       = (float*)(ws + off); off += 256;

    // ---- preprocessing: histogram -> scan -> (rel,dst) counting sort ----
    hipMemsetAsync(cur2, 0, (size_t)RN * 4, stream);    // cur2 doubles as histogram
    count_kernel<<<1024, 256, 0, stream>>>(ei, et, cur2);
    const int NB = (RN + 1023) / 1024;                   // 1954
    scan1_kernel<<<NB, 256, 0, stream>>>(cur2, off2, scan_part, RN);
    scan2_kernel<<<1, 256, 0, stream>>>(scan_part, NB);
    scan3_kernel<<<2048, 256, 0, stream>>>(off2, cur2, scan_part, RN);
    finalize_kernel<<<1, 64, 0, stream>>>(off2);
    bucket_kernel<<<2048, 256, 0, stream>>>(ei, et, cur2, e_pair);

    // ---- convert inputs / pack weights to bf16 ----
    cvt_bf16_kernel<<<2048, 256, 0, stream>>>(x, x_bf, N_NODES * F_IN / 4);
    pack_w<F_IN><<<1, 256, 0, stream>>>(w_in, wp_in);
    pack_w<H_DIM><<<L_LAYERS, 256, 0, stream>>>(root_w, wp_root);
    pack_w<H_DIM><<<L_LAYERS * R_REL, 256, 0, stream>>>(rel_w, wp_rel);

    // ---- input MLP: h = relu(x @ w_in + b_in) -> bf16 ----
    mfma_dense<F_IN, true, true, true><<<dim3(640), 256, 0, stream>>>(
        x_bf, wp_in, b_in, h_bf, N_NODES);

    // ---- RGCN layers (barrier-free fused conv, BN stats in epilogue) ----
    const int CONV_BLOCKS = (N_NODES + 63) / 64;   // 1563
    for (int l = 0; l < L_LAYERS; ++l) {
        hipMemsetAsync(bn_sums, 0, 2 * H_DIM * 4, stream);
        rgcn_conv<<<dim3(CONV_BLOCKS), 256, 0, stream>>>(
            h_bf, wp_rel + (size_t)l * R_REL * H_DIM * H_DIM,
            wp_root + (size_t)l * H_DIM * H_DIM, conv_b + (size_t)l * H_DIM,
            e_pair, off2, outb, bn_sums);
        bn_apply<<<2048, 256, 0, stream>>>(outb, bn_sums,
                                           bn_g + (size_t)l * H_DIM,
                                           bn_b + (size_t)l * H_DIM, h_bf);
    }

    // ---- global mean pool + classifier ----
    hipMemsetAsync(pool, 0, (size_t)G_GRAPHS * H_DIM * 4, stream);
    hipMemsetAsync(pcnt, 0, 256, stream);
    pool_kernel<<<512, 256, 0, stream>>>(h_bf, batch, pool, pcnt);
    logits_kernel<<<G_GRAPHS, 128, 0, stream>>>(pool, pcnt, w_out, b_out, out);
}